// Round 3
// baseline (658.494 us; speedup 1.0000x reference)
//
#include <hip/hip_runtime.h>

#define NQ    15
#define DIM   32768
#define NTOK  32
#define NPQC  60

__device__ __forceinline__ float wsum(float v){
  #pragma unroll
  for (int m = 1; m < 64; m <<= 1) v += __shfl_xor(v, m, 64);
  return v;
}

// ============================================================================
// Layout machinery (proven in round 2): 8 blocks per state, 12 local bits.
// Local position p: p==0 reg bit0; p 1..6 lane bits; p 7..9 tid bits 6..8 (LDS);
// p==10 reg bit1; p==11 reg bit2.  Positions 12..14 = block bits.
// ============================================================================

template<int CPOS>
__device__ __forceinline__ bool cbit(int r, int tid, int blk){
  if constexpr (CPOS < 0)        return true;
  else if constexpr (CPOS == 0)  return (r & 1) != 0;
  else if constexpr (CPOS == 10) return (r & 2) != 0;
  else if constexpr (CPOS == 11) return (r & 4) != 0;
  else if constexpr (CPOS <= 9)  return ((tid >> (CPOS - 1)) & 1) != 0;
  else                           return ((blk >> (CPOS - 12)) & 1) != 0;
}

template<int TPOS, int CPOS, bool RX>
__device__ __forceinline__ void gate_rl(float2 cs, float (&vr)[8], float (&vi)[8], int tid, int blk){
  constexpr int tm = (TPOS == 0) ? 1 : (TPOS == 10 ? 2 : 4);
  const float c = cs.x, s = cs.y;
  #pragma unroll
  for (int r0 = 0; r0 < 8; ++r0){
    if (r0 & tm) continue;
    const int r1 = r0 | tm;
    const bool act = cbit<CPOS>(r0, tid, blk);
    const float ar = vr[r0], ai = vi[r0], br = vr[r1], bi = vi[r1];
    if (act){
      if constexpr (RX){
        vr[r0] = fmaf(c, ar,  s * bi); vi[r0] = fmaf(c, ai, -s * br);
        vr[r1] = fmaf(c, br,  s * ai); vi[r1] = fmaf(c, bi, -s * ar);
      } else {
        vr[r0] = fmaf(c, ar, -s * br); vi[r0] = fmaf(c, ai, -s * bi);
        vr[r1] = fmaf(c, br,  s * ar); vi[r1] = fmaf(c, bi,  s * ai);
      }
    }
  }
}

template<int TPOS, int CPOS, bool RX>
__device__ __forceinline__ void gate_ln(float2 cs, float (&vr)[8], float (&vi)[8], int tid, int blk){
  constexpr int bm = 1 << (TPOS - 1);
  const float c = cs.x, s = cs.y;
  const int side = (tid >> (TPOS - 1)) & 1;
  const float sg = side ? s : -s;
  #pragma unroll
  for (int r = 0; r < 8; ++r){
    const float pr = __shfl_xor(vr[r], bm, 64);
    const float pi = __shfl_xor(vi[r], bm, 64);
    const bool act = cbit<CPOS>(r, tid, blk);
    float nr, ni;
    if constexpr (RX){ nr = fmaf(c, vr[r],  s * pi); ni = fmaf(c, vi[r], -s * pr); }
    else             { nr = fmaf(c, vr[r], sg * pr); ni = fmaf(c, vi[r], sg * pi); }
    if (act){ vr[r] = nr; vi[r] = ni; }
  }
}

template<int TPOS, int CPOS, bool RX>
__device__ __forceinline__ void gate_wv(float2 cs, float (&vr)[8], float (&vi)[8], int tid, int blk, float2* ex){
  constexpr int tb = TPOS - 1;                // 6..8
  const int ptid = tid ^ (1 << tb);
  const float c = cs.x, s = cs.y;
  const int side = (tid >> tb) & 1;
  const float sg = side ? s : -s;
  __syncthreads();
  #pragma unroll
  for (int r = 0; r < 8; ++r) ex[(r << 9) | tid] = make_float2(vr[r], vi[r]);
  __syncthreads();
  #pragma unroll
  for (int r = 0; r < 8; ++r){
    const float2 p = ex[(r << 9) | ptid];
    const bool act = cbit<CPOS>(r, tid, blk);
    float nr, ni;
    if constexpr (RX){ nr = fmaf(c, vr[r],  s * p.y); ni = fmaf(c, vi[r], -s * p.x); }
    else             { nr = fmaf(c, vr[r], sg * p.x); ni = fmaf(c, vi[r], sg * p.y); }
    if (act){ vr[r] = nr; vi[r] = ni; }
  }
}

template<int TPOS, int CPOS, bool RX>
__device__ __forceinline__ void G(float2 cs, float (&vr)[8], float (&vi)[8], int tid, int blk, float2* ex){
  if constexpr (TPOS == 0 || TPOS == 10 || TPOS == 11) gate_rl<TPOS,CPOS,RX>(cs, vr, vi, tid, blk);
  else if constexpr (TPOS <= 6)                        gate_ln<TPOS,CPOS,RX>(cs, vr, vi, tid, blk);
  else                                                 gate_wv<TPOS,CPOS,RX>(cs, vr, vi, tid, blk, ex);
}

#define SEG_LOAD(SRC)                                                        \
  {                                                                          \
    const int t2 = tid << 1;                                                 \
    _Pragma("unroll")                                                        \
    for (int rh = 0; rh < 4; ++rh){                                          \
      const int r2 = rh >> 1, r1 = rh & 1, ra = (r1 << 1) | (r2 << 2);       \
      const float4 v = *reinterpret_cast<const float4*>(&(SRC)[(r2 << 11) + (r1 << 10) + t2]); \
      vr[ra] = v.x; vi[ra] = v.y; vr[ra + 1] = v.z; vi[ra + 1] = v.w;        \
    }                                                                        \
  }

// ---------------- device-side segment bodies (verbatim from proven kernels) --

__device__ __forceinline__ void d_seg1(const float2* __restrict__ mono, float2* __restrict__ outTok,
    const float2* __restrict__ cs, const float* __restrict__ parts, int np, int finalMode,
    const float* __restrict__ qsvt, int tid, int blk, float2* ex, float2* gcs)
{
  if (tid < 12) gcs[tid] = cs[tid];
  bool small = false; float inv = 1.f;
  if (np > 0){
    const int lane = tid & 63;
    float p = lane < np ? parts[lane] : 0.f;
    const float nv = sqrtf(wsum(p));
    if (finalMode){
      const float qs = fmaxf(fabsf(qsvt[0]) + fabsf(qsvt[1]) + fabsf(qsvt[2]) + fabsf(qsvt[3]), 1e-8f);
      small = (nv / qs) < 1e-8f;
    } else small = nv < 1e-8f;
    inv = small ? 0.f : 1.f / nv;
  }
  float vr[8], vi[8];
  const float2* src = mono + (blk << 12);
  {
    const int t2 = tid << 1;
    #pragma unroll
    for (int rh = 0; rh < 4; ++rh){
      const int r2 = rh >> 1, r1 = rh & 1, ra = (r1 << 1) | (r2 << 2);
      const float4 v = *reinterpret_cast<const float4*>(&src[(r2 << 11) + (r1 << 10) + t2]);
      vr[ra] = v.x * inv; vi[ra] = v.y * inv; vr[ra + 1] = v.z * inv; vi[ra + 1] = v.w * inv;
    }
  }
  if (small){
    #pragma unroll
    for (int r = 0; r < 8; ++r){ vr[r] = (blk == 0 && tid == 0 && r == 0) ? 1.f : 0.f; vi[r] = 0.f; }
  }
  __syncthreads();
  G<11,-1,false>(gcs[0], vr, vi, tid, blk, ex);
  G<10,-1,false>(gcs[1], vr, vi, tid, blk, ex);
  G< 9,-1,false>(gcs[2], vr, vi, tid, blk, ex);
  G< 8,-1,false>(gcs[3], vr, vi, tid, blk, ex);
  G< 7,-1,false>(gcs[4], vr, vi, tid, blk, ex);
  G< 6,-1,false>(gcs[5], vr, vi, tid, blk, ex);
  G< 5,-1,false>(gcs[6], vr, vi, tid, blk, ex);
  G< 4,-1,false>(gcs[7], vr, vi, tid, blk, ex);
  G< 3,-1,false>(gcs[8], vr, vi, tid, blk, ex);
  G< 2,-1,false>(gcs[9], vr, vi, tid, blk, ex);
  G< 1,-1,false>(gcs[10], vr, vi, tid, blk, ex);
  G< 0,-1,false>(gcs[11], vr, vi, tid, blk, ex);
  float2* dst = outTok;
  const int bb = ((blk & 1) << 5) | ((blk & 2) << 5) | ((blk & 4) << 8);
  const int tb = ((tid & 15) << 1) | ((tid & 112) << 3) | ((tid & 384) << 5);
  #pragma unroll
  for (int r1 = 0; r1 < 2; ++r1)
    #pragma unroll
    for (int r0 = 0; r0 < 2; ++r0){
      const int r = r0 | (r1 << 1);
      const int a = bb + tb + (r0 << 11) + (r1 << 14);
      *reinterpret_cast<float4*>(&dst[a]) = make_float4(vr[r], vi[r], vr[r + 4], vi[r + 4]);
    }
}

__device__ __forceinline__ void d_seg2(const float2* __restrict__ inTok, float2* __restrict__ outTok,
    const float2* __restrict__ cs, int tid, int blk, float2* ex, float2* gcs)
{
  if (tid < 15) gcs[tid] = cs[12 + tid];
  float vr[8], vi[8];
  const float2* src = inTok + (blk << 12);
  SEG_LOAD(src);
  __syncthreads();
  G<10,-1,false>(gcs[0], vr, vi, tid, blk, ex);
  G< 6,-1,false>(gcs[1], vr, vi, tid, blk, ex);
  G< 5,-1,false>(gcs[2], vr, vi, tid, blk, ex);
  G< 0, 5,true >(gcs[3], vr, vi, tid, blk, ex);
  G< 5, 6,true >(gcs[4], vr, vi, tid, blk, ex);
  G< 6,10,true >(gcs[5], vr, vi, tid, blk, ex);
  G<10,11,true >(gcs[6], vr, vi, tid, blk, ex);
  G<11, 1,true >(gcs[7], vr, vi, tid, blk, ex);
  G< 1, 2,true >(gcs[8], vr, vi, tid, blk, ex);
  G< 2, 3,true >(gcs[9], vr, vi, tid, blk, ex);
  G< 3, 4,true >(gcs[10], vr, vi, tid, blk, ex);
  G< 4, 7,true >(gcs[11], vr, vi, tid, blk, ex);
  G< 7, 8,true >(gcs[12], vr, vi, tid, blk, ex);
  G< 8, 9,true >(gcs[13], vr, vi, tid, blk, ex);
  G< 9,12,true >(gcs[14], vr, vi, tid, blk, ex);
  float2* dst = outTok;
  const int bb = ((blk & 1) << 11) | ((blk & 2) << 5) | ((blk & 4) << 3);
  const int tb = ((tid & 7) << 1) | ((tid & 8) << 7) | ((tid & 16) << 8) | ((tid & 32) << 8) | ((tid & 448) << 1);
  #pragma unroll
  for (int r1 = 0; r1 < 2; ++r1)
    #pragma unroll
    for (int r0 = 0; r0 < 2; ++r0){
      const int r = r0 | (r1 << 1);
      const int a = bb + tb + (r0 << 4) + (r1 << 14);
      *reinterpret_cast<float4*>(&dst[a]) = make_float4(vr[r], vi[r], vr[r + 4], vi[r + 4]);
    }
}

__device__ __forceinline__ void d_seg3(const float2* __restrict__ inTok, float2* __restrict__ outTok,
    const float2* __restrict__ cs, int tid, int blk, float2* ex, float2* gcs)
{
  if (tid < 15) gcs[tid] = cs[27 + tid];
  float vr[8], vi[8];
  const float2* src = inTok + (blk << 12);
  SEG_LOAD(src);
  __syncthreads();
  G<11, 6,true >(gcs[0], vr, vi, tid, blk, ex);
  G< 6, 5,true >(gcs[1], vr, vi, tid, blk, ex);
  G< 5, 4,true >(gcs[2], vr, vi, tid, blk, ex);
  G< 4,-1,false>(gcs[3], vr, vi, tid, blk, ex);
  G< 5,-1,false>(gcs[4], vr, vi, tid, blk, ex);
  G< 6,-1,false>(gcs[5], vr, vi, tid, blk, ex);
  G<11,-1,false>(gcs[6], vr, vi, tid, blk, ex);
  G< 9,-1,false>(gcs[7], vr, vi, tid, blk, ex);
  G< 8,-1,false>(gcs[8], vr, vi, tid, blk, ex);
  G< 7,-1,false>(gcs[9], vr, vi, tid, blk, ex);
  G<10,-1,false>(gcs[10], vr, vi, tid, blk, ex);
  G< 3,-1,false>(gcs[11], vr, vi, tid, blk, ex);
  G< 2,-1,false>(gcs[12], vr, vi, tid, blk, ex);
  G< 1,-1,false>(gcs[13], vr, vi, tid, blk, ex);
  G< 0,-1,false>(gcs[14], vr, vi, tid, blk, ex);
  float2* dst = outTok;
  const int bb = ((blk & 1) << 5) | ((blk & 2) << 5) | ((blk & 4) << 8);
  const int tb = ((tid & 1) << 13) | ((tid & 2) << 13) | ((tid & 60) >> 1) | ((tid & 448) << 1);
  #pragma unroll
  for (int r2 = 0; r2 < 2; ++r2)
    #pragma unroll
    for (int r0 = 0; r0 < 2; ++r0){
      const int r = r0 | (r2 << 2);
      const int a = bb + tb + (r0 << 12) + (r2 << 11);
      *reinterpret_cast<float4*>(&dst[a]) = make_float4(vr[r], vi[r], vr[r + 2], vi[r + 2]);
    }
}

__device__ __forceinline__ void d_seg4(const float2* __restrict__ inTok, float2* __restrict__ outTok,
    const float2* __restrict__ cs, int tid, int blk, float2* ex, float2* gcs)
{
  if (tid < 14) gcs[tid] = cs[42 + tid];
  float vr[8], vi[8];
  const float2* src = inTok + (blk << 12);
  SEG_LOAD(src);
  __syncthreads();
  G<10,-1,false>(gcs[0], vr, vi, tid, blk, ex);
  G< 6,-1,false>(gcs[1], vr, vi, tid, blk, ex);
  G< 5,-1,false>(gcs[2], vr, vi, tid, blk, ex);
  G< 6, 5,true >(gcs[3], vr, vi, tid, blk, ex);
  G< 5, 2,true >(gcs[4], vr, vi, tid, blk, ex);
  G< 2, 3,true >(gcs[5], vr, vi, tid, blk, ex);
  G< 3, 4,true >(gcs[6], vr, vi, tid, blk, ex);
  G< 4,11,true >(gcs[7], vr, vi, tid, blk, ex);
  G<11, 9,true >(gcs[8], vr, vi, tid, blk, ex);
  G< 9, 8,true >(gcs[9], vr, vi, tid, blk, ex);
  G< 8, 7,true >(gcs[10], vr, vi, tid, blk, ex);
  G< 7, 0,true >(gcs[11], vr, vi, tid, blk, ex);
  G< 0, 1,true >(gcs[12], vr, vi, tid, blk, ex);
  G< 1,14,true >(gcs[13], vr, vi, tid, blk, ex);
  float2* dst = outTok;
  const int bb = ((blk & 1) << 10) | ((blk & 2) << 2) | ((blk & 4) << 2);
  const int tb = ((tid & 1) << 5) | ((tid & 2) << 13) | ((tid & 4) << 11) | ((tid & 8) << 9)
               | ((tid & 48) >> 3) | ((tid & 448) << 1);
  #pragma unroll
  for (int r2 = 0; r2 < 2; ++r2)
    #pragma unroll
    for (int r0 = 0; r0 < 2; ++r0){
      const int r = r0 | (r2 << 2);
      const int a = bb + tb + (r0 << 6) + (r2 << 11);
      *reinterpret_cast<float4*>(&dst[a]) = make_float4(vr[r], vi[r], vr[r + 2], vi[r + 2]);
    }
}

__device__ __forceinline__ void d_seg5(const float2* __restrict__ inTok, float2* __restrict__ outTok,
    const float2* __restrict__ cs, int tid, int blk, float2* ex, float2* gcs)
{
  if (tid < 4) gcs[tid] = cs[56 + tid];
  float vr[8], vi[8];
  const float2* src = inTok + (blk << 12);
  SEG_LOAD(src);
  __syncthreads();
  G< 4, 3,true >(gcs[0], vr, vi, tid, blk, ex);
  G< 3,10,true >(gcs[1], vr, vi, tid, blk, ex);
  G<10, 0,true >(gcs[2], vr, vi, tid, blk, ex);
  G< 0, 2,true >(gcs[3], vr, vi, tid, blk, ex);
  float2* dst = outTok;
  const int bb = blk << 9;
  const int tb = ((tid & 1) << 12) | ((tid & 2) << 12) | ((tid & 508) >> 1);
  #pragma unroll
  for (int r2 = 0; r2 < 2; ++r2)
    #pragma unroll
    for (int r0 = 0; r0 < 2; ++r0){
      const int r = r0 | (r2 << 2);
      const int a = bb + tb + (r0 << 14) + (r2 << 8);
      *reinterpret_cast<float4*>(&dst[a]) = make_float4(vr[r], vi[r], vr[r + 2], vi[r + 2]);
    }
}

__device__ __forceinline__ void d_combine(const float2* __restrict__ ev, const float2* __restrict__ lcu,
    const float* __restrict__ partsPrev, int np, const float* __restrict__ qsvt, int k,
    float2* __restrict__ mono_out, float2* __restrict__ acc,
    float* __restrict__ pMo, float* __restrict__ pAo, int bid, int tid, float* red)
{
  const int d = (bid << 9) | tid;
  float scale = 1.f;
  if (np > 0){
    const int lane = tid & 63;
    float p = lane < np ? partsPrev[lane] : 0.f;
    const float nv = sqrtf(wsum(p));
    scale = (nv < 1e-8f) ? 1.f : nv;
  }
  float sr = 0.f, si = 0.f;
  #pragma unroll
  for (int t = 0; t < NTOK; ++t){
    const float2 e = ev[((size_t)t << 15) + d];
    const float2 c = lcu[t];
    sr += e.x * c.x - e.y * c.y;
    si += e.x * c.y + e.y * c.x;
  }
  sr *= scale; si *= scale;
  mono_out[d] = make_float2(sr, si);
  const float q = qsvt[k];
  float2 a = acc[d];
  a = make_float2(fmaf(q, sr, a.x), fmaf(q, si, a.y));
  acc[d] = a;
  float m2 = fmaf(sr, sr, si * si);
  float a2 = fmaf(a.x, a.x, a.y * a.y);
  m2 = wsum(m2); a2 = wsum(a2);
  const int lane = tid & 63, wv = tid >> 6;
  if (lane == 0){ red[wv] = m2; red[8 + wv] = a2; }
  __syncthreads();
  if (tid == 0){
    float t1 = 0.f, t2 = 0.f;
    for (int i = 0; i < 8; ++i){ t1 += red[i]; t2 += red[8 + i]; }
    pMo[bid] = t1; pAo[bid] = t2;
  }
}

// ---------------- device-scope counting barrier ------------------------------
__device__ __forceinline__ void bar_arrive_wait(unsigned* cnt, unsigned target){
  __syncthreads();
  if (threadIdx.x == 0){
    __threadfence();                      // release: flush this XCD's writes
    atomicAdd(cnt, 1u);
    while (atomicAdd(cnt, 0u) < target) __builtin_amdgcn_s_sleep(4);
    __threadfence();                      // acquire: invalidate stale caches
  }
  __syncthreads();
}

// ---------------- mega kernel: whole QSVT pipeline in one launch -------------
__global__ __launch_bounds__(512) void mega_k(
    const float2* __restrict__ csarr, const float2* __restrict__ csf,
    const float2* __restrict__ lcu, const float* __restrict__ qsvt,
    float2* monoA, float2* monoB, float2* acc, float2* fin,
    float2* bufA, float2* bufB,
    float* pM, float* pA, float* partials, float* out,
    unsigned* tcnt, unsigned* gcnt)
{
  __shared__ float2 ex[4096];
  __shared__ float2 gcs[16];
  __shared__ float red[16];
  __shared__ float sredx[8][16], sredy[8][16], sredz[8][16];
  const int tid = threadIdx.x;
  const int bid = blockIdx.x;
  const int blk = bid & 7, tok = bid >> 3;
  int tgen = 0, ggen = 0;
  float2* const bA = bufA + ((size_t)tok << 15);
  float2* const bB = bufB + ((size_t)tok << 15);
  const float2* const csTok = csarr + tok * NPQC;

  #pragma unroll 1
  for (int r = 0; r < 3; ++r){
    const float2* min_ = (r & 1) ? monoB : monoA;
    float2* mout       = (r & 1) ? monoA : monoB;
    const float* prevPM = (r == 0) ? (const float*)nullptr : (pM + (size_t)(r - 1) * 64);
    const int np = (r == 0) ? 0 : 64;
    d_seg1(min_, bA, csTok, prevPM, np, 0, qsvt, tid, blk, ex, gcs);
    bar_arrive_wait(tcnt + tok, 8u * (unsigned)(++tgen));
    d_seg2(bA, bB, csTok, tid, blk, ex, gcs);
    bar_arrive_wait(tcnt + tok, 8u * (unsigned)(++tgen));
    d_seg3(bB, bA, csTok, tid, blk, ex, gcs);
    bar_arrive_wait(tcnt + tok, 8u * (unsigned)(++tgen));
    d_seg4(bA, bB, csTok, tid, blk, ex, gcs);
    bar_arrive_wait(tcnt + tok, 8u * (unsigned)(++tgen));
    d_seg5(bB, bA, csTok, tid, blk, ex, gcs);
    bar_arrive_wait(gcnt, 256u * (unsigned)(++ggen));
    if (bid < 64)
      d_combine(bufA, lcu, prevPM, np, qsvt, r + 1, mout, acc, pM + (size_t)r * 64, pA, bid, tid, red);
    bar_arrive_wait(gcnt, 256u * (unsigned)(++ggen));
  }

  // final evolution of acc with ff params (token 0's 8 blocks)
  if (tok == 0){
    d_seg1(acc, bufA, csf, pA, 64, 1, qsvt, tid, blk, ex, gcs);
    bar_arrive_wait(tcnt + tok, 8u * (unsigned)(++tgen));
    d_seg2(bufA, bufB, csf, tid, blk, ex, gcs);
    bar_arrive_wait(tcnt + tok, 8u * (unsigned)(++tgen));
    d_seg3(bufB, bufA, csf, tid, blk, ex, gcs);
    bar_arrive_wait(tcnt + tok, 8u * (unsigned)(++tgen));
    d_seg4(bufA, bufB, csf, tid, blk, ex, gcs);
    bar_arrive_wait(tcnt + tok, 8u * (unsigned)(++tgen));
    d_seg5(bufB, fin, csf, tid, blk, ex, gcs);
  }
  bar_arrive_wait(gcnt, 256u * (unsigned)(++ggen));

  // parallel measurement stage A: 64 blocks, 512 amps each, L1 layout
  if (bid < 64){
    const int g = (bid << 9) | tid;
    const float2 a = fin[g];
    ex[tid] = a;
    __syncthreads();
    const int lane = tid & 63, wv = tid >> 6;
    const int abit[15] = {11,10,9,8,7,6,5,4,3,2,1,0,14,13,12};
    #pragma unroll
    for (int w = 0; w < 15; ++w){
      const int ab = abit[w];
      const int m = 1 << ab;
      float2 p;
      if (ab < 6){ p.x = __shfl_xor(a.x, m, 64); p.y = __shfl_xor(a.y, m, 64); }
      else if (ab < 9){ p = ex[tid ^ m]; }
      else { p = fin[g ^ m]; }
      const bool lower = (g & m) == 0;
      float x = lower ? (a.x * p.x + a.y * p.y) : 0.f;
      float y = lower ? (a.x * p.y - a.y * p.x) : 0.f;
      float z = (lower ? 1.f : -1.f) * (a.x * a.x + a.y * a.y);
      x = wsum(x); y = wsum(y); z = wsum(z);
      if (lane == 0){ sredx[wv][w] = x; sredy[wv][w] = y; sredz[wv][w] = z; }
    }
    __syncthreads();
    if (tid < 45){
      const int plane = tid / 15, w = tid % 15;
      float s = 0.f;
      #pragma unroll
      for (int i = 0; i < 8; ++i)
        s += (plane == 0) ? sredx[i][w] : (plane == 1) ? sredy[i][w] : sredz[i][w];
      partials[bid * 45 + tid] = (plane < 2 ? 2.f : 1.f) * s;
    }
  }
  bar_arrive_wait(gcnt, 256u * (unsigned)(++ggen));
  if (bid == 0 && tid < 45){
    float s = 0.f;
    for (int i = 0; i < 64; ++i) s += partials[i * 45 + tid];
    out[tid] = s;
  }
}

// ---------------- fallback multi-launch wrappers (proven path) ---------------

__global__ __launch_bounds__(512) void seg1_k(const float2* __restrict__ in, float2* __restrict__ out,
    const float2* __restrict__ cs, int csStride, const float* __restrict__ parts, int np,
    int finalMode, const float* __restrict__ qsvt)
{
  __shared__ float2 ex[4096]; __shared__ float2 gcs[16];
  d_seg1(in, out + ((size_t)blockIdx.y << 15), cs + blockIdx.y * csStride, parts, np, finalMode, qsvt,
         threadIdx.x, blockIdx.x, ex, gcs);
}
__global__ __launch_bounds__(512) void seg2_k(const float2* __restrict__ in, float2* __restrict__ out,
    const float2* __restrict__ cs, int csStride)
{
  __shared__ float2 ex[4096]; __shared__ float2 gcs[16];
  d_seg2(in + ((size_t)blockIdx.y << 15), out + ((size_t)blockIdx.y << 15), cs + blockIdx.y * csStride,
         threadIdx.x, blockIdx.x, ex, gcs);
}
__global__ __launch_bounds__(512) void seg3_k(const float2* __restrict__ in, float2* __restrict__ out,
    const float2* __restrict__ cs, int csStride)
{
  __shared__ float2 ex[4096]; __shared__ float2 gcs[16];
  d_seg3(in + ((size_t)blockIdx.y << 15), out + ((size_t)blockIdx.y << 15), cs + blockIdx.y * csStride,
         threadIdx.x, blockIdx.x, ex, gcs);
}
__global__ __launch_bounds__(512) void seg4_k(const float2* __restrict__ in, float2* __restrict__ out,
    const float2* __restrict__ cs, int csStride)
{
  __shared__ float2 ex[4096]; __shared__ float2 gcs[16];
  d_seg4(in + ((size_t)blockIdx.y << 15), out + ((size_t)blockIdx.y << 15), cs + blockIdx.y * csStride,
         threadIdx.x, blockIdx.x, ex, gcs);
}
__global__ __launch_bounds__(512) void seg5_k(const float2* __restrict__ in, float2* __restrict__ out,
    const float2* __restrict__ cs, int csStride)
{
  __shared__ float2 ex[4096]; __shared__ float2 gcs[16];
  d_seg5(in + ((size_t)blockIdx.y << 15), out + ((size_t)blockIdx.y << 15), cs + blockIdx.y * csStride,
         threadIdx.x, blockIdx.x, ex, gcs);
}
__global__ __launch_bounds__(512) void combine2_k(const float2* __restrict__ ev, const float2* __restrict__ lcu,
    const float* __restrict__ partsPrev, int np, const float* __restrict__ qsvt, int k,
    float2* __restrict__ mono_out, float2* __restrict__ acc,
    float* __restrict__ pM, float* __restrict__ pA)
{
  __shared__ float red[16];
  d_combine(ev, lcu, partsPrev, np, qsvt, k, mono_out, acc, pM, pA, blockIdx.x, threadIdx.x, red);
}

__global__ void measure_l1(const float2* __restrict__ st, float* __restrict__ out)
{
  __shared__ float rx[16], ryy[16], rz[16];
  const int tid = threadIdx.x;          // 1024
  const int lane = tid & 63, wv = tid >> 6;
  const int abit[15] = {11,10,9,8,7,6,5,4,3,2,1,0,14,13,12};
  for (int w = 0; w < NQ; ++w){
    const int ab = abit[w];
    const int m = 1 << ab;
    float x = 0.f, y = 0.f, z = 0.f;
    for (int d = tid; d < DIM / 2; d += 1024){
      const int i0 = ((d >> ab) << (ab + 1)) | (d & (m - 1));
      const float2 a0 = st[i0];
      const float2 a1 = st[i0 | m];
      x += a0.x * a1.x + a0.y * a1.y;
      y += a0.x * a1.y - a0.y * a1.x;
      z += (a0.x * a0.x + a0.y * a0.y) - (a1.x * a1.x + a1.y * a1.y);
    }
    x = wsum(x); y = wsum(y); z = wsum(z);
    if (lane == 0){ rx[wv] = x; ryy[wv] = y; rz[wv] = z; }
    __syncthreads();
    if (tid == 0){
      float sx = 0.f, sy = 0.f, sz = 0.f;
      for (int i = 0; i < 16; ++i){ sx += rx[i]; sy += ryy[i]; sz += rz[i]; }
      out[w] = 2.0f * sx; out[NQ + w] = 2.0f * sy; out[2 * NQ + w] = sz;
    }
    __syncthreads();
  }
}

// ---------------- small setup kernels ---------------------------------------

__global__ void angles2_kernel(const float* __restrict__ emb, const float* __restrict__ W,
                               const float* __restrict__ b, float2* __restrict__ csarr)
{
  const int p = blockIdx.x, t = blockIdx.y, lane = threadIdx.x;
  const float* er = emb + (size_t)t * 1024;
  const float* wr = W + (size_t)p * 1024;
  float s = 0.f;
  for (int i = lane; i < 1024; i += 64) s = fmaf(er[i], wr[i], s);
  s = wsum(s);
  if (lane == 0){
    const float a = (s + b[p]) * 0.5f;
    csarr[t * NPQC + p] = make_float2(cosf(a), sinf(a));
  }
}

__global__ void prep_kernel(const float* __restrict__ ri, float2* __restrict__ lcu,
                            const float* __restrict__ ffp, float2* __restrict__ csf)
{
  const int t = threadIdx.x;   // 64
  float re = 0.f, im = 0.f, mag = 0.f;
  if (t < NTOK){ re = ri[2 * t]; im = ri[2 * t + 1]; mag = sqrtf(re * re + im * im); }
  const float ssum = wsum(mag);
  const float denom = fmaxf(ssum, 1e-8f);
  if (t < NTOK) lcu[t] = make_float2(re / denom, im / denom);
  if (t < NPQC){ const float a = ffp[t] * 0.5f; csf[t] = make_float2(cosf(a), sinf(a)); }
}

__global__ void init3_kernel(float2* __restrict__ monoA, float2* __restrict__ acc,
                             const float* __restrict__ qsvt, unsigned* __restrict__ cnts)
{
  const int d = (blockIdx.x << 9) | threadIdx.x;
  monoA[d] = make_float2(d == 0 ? 1.f : 0.f, 0.f);
  acc[d]   = make_float2(d == 0 ? qsvt[0] : 0.f, 0.f);
  if (d < 40) cnts[d] = 0u;
}

// ============================================================================

extern "C" void kernel_launch(void* const* d_in, const int* in_sizes, int n_in,
                              void* d_out, int out_size, void* d_ws, size_t ws_size,
                              hipStream_t stream)
{
  const float* emb   = (const float*)d_in[0];
  const float* W     = (const float*)d_in[1];
  const float* b     = (const float*)d_in[2];
  const float* qsvt  = (const float*)d_in[3];
  const float* lcuri = (const float*)d_in[4];
  const float* ffp   = (const float*)d_in[5];
  float* out = (float*)d_out;

  char* ws = (char*)d_ws;
  size_t off = 0;
  auto nxt = [&](size_t bytes) { size_t o = off; off = (off + bytes + 255) & ~(size_t)255; return o; };

  const size_t o_cs   = nxt((size_t)NTOK * NPQC * sizeof(float2));
  const size_t o_csf  = nxt(NPQC * sizeof(float2));
  const size_t o_lcu2 = nxt(NTOK * sizeof(float2));
  const size_t o_pm   = nxt(3 * 64 * sizeof(float));
  const size_t o_pa   = nxt(64 * sizeof(float));
  const size_t o_part = nxt(64 * 45 * sizeof(float));
  const size_t o_cnt  = nxt(64 * sizeof(unsigned));
  const size_t o_mA2  = nxt((size_t)DIM * sizeof(float2));
  const size_t o_mB2  = nxt((size_t)DIM * sizeof(float2));
  const size_t o_acc2 = nxt((size_t)DIM * sizeof(float2));
  const size_t o_fin2 = nxt((size_t)DIM * sizeof(float2));
  const size_t o_bufA = nxt((size_t)NTOK * DIM * sizeof(float2));
  const size_t o_bufB = nxt((size_t)NTOK * DIM * sizeof(float2));
  const size_t need = off;

  float2* csarr = (float2*)(ws + o_cs);
  float2* csf   = (float2*)(ws + o_csf);
  float2* lcu   = (float2*)(ws + o_lcu2);
  float*  pMbuf = (float*)(ws + o_pm);
  float*  pA    = (float*)(ws + o_pa);
  float*  parts = (float*)(ws + o_part);
  unsigned* cnts = (unsigned*)(ws + o_cnt);
  float2* monoA = (float2*)(ws + o_mA2);
  float2* monoB = (float2*)(ws + o_mB2);
  float2* acc   = (float2*)(ws + o_acc2);
  float2* fin   = (float2*)(ws + o_fin2);
  float2* bufA  = (float2*)(ws + o_bufA);
  float2* bufB  = (float2*)(ws + o_bufB);

  angles2_kernel<<<dim3(NPQC, NTOK), 64, 0, stream>>>(emb, W, b, csarr);
  prep_kernel<<<1, 64, 0, stream>>>(lcuri, lcu, ffp, csf);
  init3_kernel<<<64, 512, 0, stream>>>(monoA, acc, qsvt, cnts);

  if (ws_size >= need) {
    // single persistent kernel: 256 blocks (co-resident: 1 block/CU at 34.5 KB
    // LDS / 8 waves), token-local + grid counting barriers, fused measurement.
    mega_k<<<256, 512, 0, stream>>>(csarr, csf, lcu, qsvt,
                                    monoA, monoB, acc, fin, bufA, bufB,
                                    pMbuf, pA, parts, out, cnts, cnts + 32);
    return;
  }

  // fallback: proven multi-launch path (round 2, 334 us)
  float2* mIn = monoA;
  float2* mOut = monoB;
  const float* prevPM = nullptr;
  for (int k = 1; k <= 3; ++k) {
    const int np = prevPM ? 64 : 0;
    seg1_k<<<dim3(8, NTOK), 512, 0, stream>>>(mIn, bufA, csarr, NPQC, prevPM, np, 0, qsvt);
    seg2_k<<<dim3(8, NTOK), 512, 0, stream>>>(bufA, bufB, csarr, NPQC);
    seg3_k<<<dim3(8, NTOK), 512, 0, stream>>>(bufB, bufA, csarr, NPQC);
    seg4_k<<<dim3(8, NTOK), 512, 0, stream>>>(bufA, bufB, csarr, NPQC);
    seg5_k<<<dim3(8, NTOK), 512, 0, stream>>>(bufB, bufA, csarr, NPQC);
    float* pMk = pMbuf + (size_t)(k - 1) * 64;
    combine2_k<<<64, 512, 0, stream>>>(bufA, lcu, prevPM, np, qsvt, k, mOut, acc, pMk, pA);
    prevPM = pMk;
    float2* tmp = mIn; mIn = mOut; mOut = tmp;
  }
  seg1_k<<<dim3(8, 1), 512, 0, stream>>>(acc, bufA, csf, 0, pA, 64, 1, qsvt);
  seg2_k<<<dim3(8, 1), 512, 0, stream>>>(bufA, bufB, csf, 0);
  seg3_k<<<dim3(8, 1), 512, 0, stream>>>(bufB, bufA, csf, 0);
  seg4_k<<<dim3(8, 1), 512, 0, stream>>>(bufA, bufB, csf, 0);
  seg5_k<<<dim3(8, 1), 512, 0, stream>>>(bufB, fin, csf, 0);
  measure_l1<<<1, 1024, 0, stream>>>(fin, out);
}

// Round 5
// 369.216 us; speedup vs baseline: 1.7835x; 1.7835x over previous
//
#include <hip/hip_runtime.h>

#define NQ    15
#define DIM   32768
#define NTOK  32
#define NPQC  60

__device__ __forceinline__ float wsum(float v){
  #pragma unroll
  for (int m = 1; m < 64; m <<= 1) v += __shfl_xor(v, m, 64);
  return v;
}

// ============================================================================
// Layout machinery (proven rounds 2-3): 8 blocks per state, 12 local bits.
// Local position p: p==0 reg bit0; p 1..6 lane bits; p 7..9 tid bits 6..8 (LDS);
// p==10 reg bit1; p==11 reg bit2.  Positions 12..14 = block bits.
// ============================================================================

template<int CPOS>
__device__ __forceinline__ bool cbit(int r, int tid, int blk){
  if constexpr (CPOS < 0)        return true;
  else if constexpr (CPOS == 0)  return (r & 1) != 0;
  else if constexpr (CPOS == 10) return (r & 2) != 0;
  else if constexpr (CPOS == 11) return (r & 4) != 0;
  else if constexpr (CPOS <= 9)  return ((tid >> (CPOS - 1)) & 1) != 0;
  else                           return ((blk >> (CPOS - 12)) & 1) != 0;
}

template<int TPOS, int CPOS, bool RX>
__device__ __forceinline__ void gate_rl(float2 cs, float (&vr)[8], float (&vi)[8], int tid, int blk){
  constexpr int tm = (TPOS == 0) ? 1 : (TPOS == 10 ? 2 : 4);
  const float c = cs.x, s = cs.y;
  #pragma unroll
  for (int r0 = 0; r0 < 8; ++r0){
    if (r0 & tm) continue;
    const int r1 = r0 | tm;
    const bool act = cbit<CPOS>(r0, tid, blk);
    const float ar = vr[r0], ai = vi[r0], br = vr[r1], bi = vi[r1];
    if (act){
      if constexpr (RX){
        vr[r0] = fmaf(c, ar,  s * bi); vi[r0] = fmaf(c, ai, -s * br);
        vr[r1] = fmaf(c, br,  s * ai); vi[r1] = fmaf(c, bi, -s * ar);
      } else {
        vr[r0] = fmaf(c, ar, -s * br); vi[r0] = fmaf(c, ai, -s * bi);
        vr[r1] = fmaf(c, br,  s * ar); vi[r1] = fmaf(c, bi,  s * ai);
      }
    }
  }
}

template<int TPOS, int CPOS, bool RX>
__device__ __forceinline__ void gate_ln(float2 cs, float (&vr)[8], float (&vi)[8], int tid, int blk){
  constexpr int bm = 1 << (TPOS - 1);
  const float c = cs.x, s = cs.y;
  const int side = (tid >> (TPOS - 1)) & 1;
  const float sg = side ? s : -s;
  #pragma unroll
  for (int r = 0; r < 8; ++r){
    const float pr = __shfl_xor(vr[r], bm, 64);
    const float pi = __shfl_xor(vi[r], bm, 64);
    const bool act = cbit<CPOS>(r, tid, blk);
    float nr, ni;
    if constexpr (RX){ nr = fmaf(c, vr[r],  s * pi); ni = fmaf(c, vi[r], -s * pr); }
    else             { nr = fmaf(c, vr[r], sg * pr); ni = fmaf(c, vi[r], sg * pi); }
    if (act){ vr[r] = nr; vi[r] = ni; }
  }
}

template<int TPOS, int CPOS, bool RX>
__device__ __forceinline__ void gate_wv(float2 cs, float (&vr)[8], float (&vi)[8], int tid, int blk, float2* ex){
  constexpr int tb = TPOS - 1;                // 6..8
  const int ptid = tid ^ (1 << tb);
  const float c = cs.x, s = cs.y;
  const int side = (tid >> tb) & 1;
  const float sg = side ? s : -s;
  __syncthreads();
  #pragma unroll
  for (int r = 0; r < 8; ++r) ex[(r << 9) | tid] = make_float2(vr[r], vi[r]);
  __syncthreads();
  #pragma unroll
  for (int r = 0; r < 8; ++r){
    const float2 p = ex[(r << 9) | ptid];
    const bool act = cbit<CPOS>(r, tid, blk);
    float nr, ni;
    if constexpr (RX){ nr = fmaf(c, vr[r],  s * p.y); ni = fmaf(c, vi[r], -s * p.x); }
    else             { nr = fmaf(c, vr[r], sg * p.x); ni = fmaf(c, vi[r], sg * p.y); }
    if (act){ vr[r] = nr; vi[r] = ni; }
  }
}

template<int TPOS, int CPOS, bool RX>
__device__ __forceinline__ void G(float2 cs, float (&vr)[8], float (&vi)[8], int tid, int blk, float2* ex){
  if constexpr (TPOS == 0 || TPOS == 10 || TPOS == 11) gate_rl<TPOS,CPOS,RX>(cs, vr, vi, tid, blk);
  else if constexpr (TPOS <= 6)                        gate_ln<TPOS,CPOS,RX>(cs, vr, vi, tid, blk);
  else                                                 gate_wv<TPOS,CPOS,RX>(cs, vr, vi, tid, blk, ex);
}

#define SEG_LOAD(SRC)                                                        \
  {                                                                          \
    const int t2 = tid << 1;                                                 \
    _Pragma("unroll")                                                        \
    for (int rh = 0; rh < 4; ++rh){                                          \
      const int r2 = rh >> 1, r1 = rh & 1, ra = (r1 << 1) | (r2 << 2);       \
      const float4 v = *reinterpret_cast<const float4*>(&(SRC)[(r2 << 11) + (r1 << 10) + t2]); \
      vr[ra] = v.x; vi[ra] = v.y; vr[ra + 1] = v.z; vi[ra + 1] = v.w;        \
    }                                                                        \
  }

// ---------------- device-side segment bodies (verbatim, proven) -------------

__device__ __forceinline__ void d_seg1(const float2* __restrict__ mono, float2* __restrict__ outTok,
    const float2* __restrict__ cs, const float* __restrict__ parts, int np, int finalMode,
    const float* __restrict__ qsvt, int tid, int blk, float2* ex, float2* gcs)
{
  if (tid < 12) gcs[tid] = cs[tid];
  bool small = false; float inv = 1.f;
  if (np > 0){
    const int lane = tid & 63;
    float p = lane < np ? parts[lane] : 0.f;
    const float nv = sqrtf(wsum(p));
    if (finalMode){
      const float qs = fmaxf(fabsf(qsvt[0]) + fabsf(qsvt[1]) + fabsf(qsvt[2]) + fabsf(qsvt[3]), 1e-8f);
      small = (nv / qs) < 1e-8f;
    } else small = nv < 1e-8f;
    inv = small ? 0.f : 1.f / nv;
  }
  float vr[8], vi[8];
  const float2* src = mono + (blk << 12);
  {
    const int t2 = tid << 1;
    #pragma unroll
    for (int rh = 0; rh < 4; ++rh){
      const int r2 = rh >> 1, r1 = rh & 1, ra = (r1 << 1) | (r2 << 2);
      const float4 v = *reinterpret_cast<const float4*>(&src[(r2 << 11) + (r1 << 10) + t2]);
      vr[ra] = v.x * inv; vi[ra] = v.y * inv; vr[ra + 1] = v.z * inv; vi[ra + 1] = v.w * inv;
    }
  }
  if (small){
    #pragma unroll
    for (int r = 0; r < 8; ++r){ vr[r] = (blk == 0 && tid == 0 && r == 0) ? 1.f : 0.f; vi[r] = 0.f; }
  }
  __syncthreads();
  G<11,-1,false>(gcs[0], vr, vi, tid, blk, ex);
  G<10,-1,false>(gcs[1], vr, vi, tid, blk, ex);
  G< 9,-1,false>(gcs[2], vr, vi, tid, blk, ex);
  G< 8,-1,false>(gcs[3], vr, vi, tid, blk, ex);
  G< 7,-1,false>(gcs[4], vr, vi, tid, blk, ex);
  G< 6,-1,false>(gcs[5], vr, vi, tid, blk, ex);
  G< 5,-1,false>(gcs[6], vr, vi, tid, blk, ex);
  G< 4,-1,false>(gcs[7], vr, vi, tid, blk, ex);
  G< 3,-1,false>(gcs[8], vr, vi, tid, blk, ex);
  G< 2,-1,false>(gcs[9], vr, vi, tid, blk, ex);
  G< 1,-1,false>(gcs[10], vr, vi, tid, blk, ex);
  G< 0,-1,false>(gcs[11], vr, vi, tid, blk, ex);
  float2* dst = outTok;
  const int bb = ((blk & 1) << 5) | ((blk & 2) << 5) | ((blk & 4) << 8);
  const int tb = ((tid & 15) << 1) | ((tid & 112) << 3) | ((tid & 384) << 5);
  #pragma unroll
  for (int r1 = 0; r1 < 2; ++r1)
    #pragma unroll
    for (int r0 = 0; r0 < 2; ++r0){
      const int r = r0 | (r1 << 1);
      const int a = bb + tb + (r0 << 11) + (r1 << 14);
      *reinterpret_cast<float4*>(&dst[a]) = make_float4(vr[r], vi[r], vr[r + 4], vi[r + 4]);
    }
}

__device__ __forceinline__ void d_seg2(const float2* __restrict__ inTok, float2* __restrict__ outTok,
    const float2* __restrict__ cs, int tid, int blk, float2* ex, float2* gcs)
{
  if (tid < 15) gcs[tid] = cs[12 + tid];
  float vr[8], vi[8];
  const float2* src = inTok + (blk << 12);
  SEG_LOAD(src);
  __syncthreads();
  G<10,-1,false>(gcs[0], vr, vi, tid, blk, ex);
  G< 6,-1,false>(gcs[1], vr, vi, tid, blk, ex);
  G< 5,-1,false>(gcs[2], vr, vi, tid, blk, ex);
  G< 0, 5,true >(gcs[3], vr, vi, tid, blk, ex);
  G< 5, 6,true >(gcs[4], vr, vi, tid, blk, ex);
  G< 6,10,true >(gcs[5], vr, vi, tid, blk, ex);
  G<10,11,true >(gcs[6], vr, vi, tid, blk, ex);
  G<11, 1,true >(gcs[7], vr, vi, tid, blk, ex);
  G< 1, 2,true >(gcs[8], vr, vi, tid, blk, ex);
  G< 2, 3,true >(gcs[9], vr, vi, tid, blk, ex);
  G< 3, 4,true >(gcs[10], vr, vi, tid, blk, ex);
  G< 4, 7,true >(gcs[11], vr, vi, tid, blk, ex);
  G< 7, 8,true >(gcs[12], vr, vi, tid, blk, ex);
  G< 8, 9,true >(gcs[13], vr, vi, tid, blk, ex);
  G< 9,12,true >(gcs[14], vr, vi, tid, blk, ex);
  float2* dst = outTok;
  const int bb = ((blk & 1) << 11) | ((blk & 2) << 5) | ((blk & 4) << 3);
  const int tb = ((tid & 7) << 1) | ((tid & 8) << 7) | ((tid & 16) << 8) | ((tid & 32) << 8) | ((tid & 448) << 1);
  #pragma unroll
  for (int r1 = 0; r1 < 2; ++r1)
    #pragma unroll
    for (int r0 = 0; r0 < 2; ++r0){
      const int r = r0 | (r1 << 1);
      const int a = bb + tb + (r0 << 4) + (r1 << 14);
      *reinterpret_cast<float4*>(&dst[a]) = make_float4(vr[r], vi[r], vr[r + 4], vi[r + 4]);
    }
}

__device__ __forceinline__ void d_seg3(const float2* __restrict__ inTok, float2* __restrict__ outTok,
    const float2* __restrict__ cs, int tid, int blk, float2* ex, float2* gcs)
{
  if (tid < 15) gcs[tid] = cs[27 + tid];
  float vr[8], vi[8];
  const float2* src = inTok + (blk << 12);
  SEG_LOAD(src);
  __syncthreads();
  G<11, 6,true >(gcs[0], vr, vi, tid, blk, ex);
  G< 6, 5,true >(gcs[1], vr, vi, tid, blk, ex);
  G< 5, 4,true >(gcs[2], vr, vi, tid, blk, ex);
  G< 4,-1,false>(gcs[3], vr, vi, tid, blk, ex);
  G< 5,-1,false>(gcs[4], vr, vi, tid, blk, ex);
  G< 6,-1,false>(gcs[5], vr, vi, tid, blk, ex);
  G<11,-1,false>(gcs[6], vr, vi, tid, blk, ex);
  G< 9,-1,false>(gcs[7], vr, vi, tid, blk, ex);
  G< 8,-1,false>(gcs[8], vr, vi, tid, blk, ex);
  G< 7,-1,false>(gcs[9], vr, vi, tid, blk, ex);
  G<10,-1,false>(gcs[10], vr, vi, tid, blk, ex);
  G< 3,-1,false>(gcs[11], vr, vi, tid, blk, ex);
  G< 2,-1,false>(gcs[12], vr, vi, tid, blk, ex);
  G< 1,-1,false>(gcs[13], vr, vi, tid, blk, ex);
  G< 0,-1,false>(gcs[14], vr, vi, tid, blk, ex);
  float2* dst = outTok;
  const int bb = ((blk & 1) << 5) | ((blk & 2) << 5) | ((blk & 4) << 8);
  const int tb = ((tid & 1) << 13) | ((tid & 2) << 13) | ((tid & 60) >> 1) | ((tid & 448) << 1);
  #pragma unroll
  for (int r2 = 0; r2 < 2; ++r2)
    #pragma unroll
    for (int r0 = 0; r0 < 2; ++r0){
      const int r = r0 | (r2 << 2);
      const int a = bb + tb + (r0 << 12) + (r2 << 11);
      *reinterpret_cast<float4*>(&dst[a]) = make_float4(vr[r], vi[r], vr[r + 2], vi[r + 2]);
    }
}

__device__ __forceinline__ void d_seg4(const float2* __restrict__ inTok, float2* __restrict__ outTok,
    const float2* __restrict__ cs, int tid, int blk, float2* ex, float2* gcs)
{
  if (tid < 14) gcs[tid] = cs[42 + tid];
  float vr[8], vi[8];
  const float2* src = inTok + (blk << 12);
  SEG_LOAD(src);
  __syncthreads();
  G<10,-1,false>(gcs[0], vr, vi, tid, blk, ex);
  G< 6,-1,false>(gcs[1], vr, vi, tid, blk, ex);
  G< 5,-1,false>(gcs[2], vr, vi, tid, blk, ex);
  G< 6, 5,true >(gcs[3], vr, vi, tid, blk, ex);
  G< 5, 2,true >(gcs[4], vr, vi, tid, blk, ex);
  G< 2, 3,true >(gcs[5], vr, vi, tid, blk, ex);
  G< 3, 4,true >(gcs[6], vr, vi, tid, blk, ex);
  G< 4,11,true >(gcs[7], vr, vi, tid, blk, ex);
  G<11, 9,true >(gcs[8], vr, vi, tid, blk, ex);
  G< 9, 8,true >(gcs[9], vr, vi, tid, blk, ex);
  G< 8, 7,true >(gcs[10], vr, vi, tid, blk, ex);
  G< 7, 0,true >(gcs[11], vr, vi, tid, blk, ex);
  G< 0, 1,true >(gcs[12], vr, vi, tid, blk, ex);
  G< 1,14,true >(gcs[13], vr, vi, tid, blk, ex);
  float2* dst = outTok;
  const int bb = ((blk & 1) << 10) | ((blk & 2) << 2) | ((blk & 4) << 2);
  const int tb = ((tid & 1) << 5) | ((tid & 2) << 13) | ((tid & 4) << 11) | ((tid & 8) << 9)
               | ((tid & 48) >> 3) | ((tid & 448) << 1);
  #pragma unroll
  for (int r2 = 0; r2 < 2; ++r2)
    #pragma unroll
    for (int r0 = 0; r0 < 2; ++r0){
      const int r = r0 | (r2 << 2);
      const int a = bb + tb + (r0 << 6) + (r2 << 11);
      *reinterpret_cast<float4*>(&dst[a]) = make_float4(vr[r], vi[r], vr[r + 2], vi[r + 2]);
    }
}

__device__ __forceinline__ void d_seg5(const float2* __restrict__ inTok, float2* __restrict__ outTok,
    const float2* __restrict__ cs, int tid, int blk, float2* ex, float2* gcs)
{
  if (tid < 4) gcs[tid] = cs[56 + tid];
  float vr[8], vi[8];
  const float2* src = inTok + (blk << 12);
  SEG_LOAD(src);
  __syncthreads();
  G< 4, 3,true >(gcs[0], vr, vi, tid, blk, ex);
  G< 3,10,true >(gcs[1], vr, vi, tid, blk, ex);
  G<10, 0,true >(gcs[2], vr, vi, tid, blk, ex);
  G< 0, 2,true >(gcs[3], vr, vi, tid, blk, ex);
  float2* dst = outTok;
  const int bb = blk << 9;
  const int tb = ((tid & 1) << 12) | ((tid & 2) << 12) | ((tid & 508) >> 1);
  #pragma unroll
  for (int r2 = 0; r2 < 2; ++r2)
    #pragma unroll
    for (int r0 = 0; r0 < 2; ++r0){
      const int r = r0 | (r2 << 2);
      const int a = bb + tb + (r0 << 14) + (r2 << 8);
      *reinterpret_cast<float4*>(&dst[a]) = make_float4(vr[r], vi[r], vr[r + 2], vi[r + 2]);
    }
}

__device__ __forceinline__ void d_combine(const float2* __restrict__ ev, const float2* __restrict__ lcu,
    const float* __restrict__ partsPrev, int np, const float* __restrict__ qsvt, int k,
    float2* __restrict__ mono_out, float2* __restrict__ acc,
    float* __restrict__ pMo, float* __restrict__ pAo, int bid, int tid, float* red)
{
  const int d = (bid << 9) | tid;
  float scale = 1.f;
  if (np > 0){
    const int lane = tid & 63;
    float p = lane < np ? partsPrev[lane] : 0.f;
    const float nv = sqrtf(wsum(p));
    scale = (nv < 1e-8f) ? 1.f : nv;
  }
  float sr = 0.f, si = 0.f;
  #pragma unroll
  for (int t = 0; t < NTOK; ++t){
    const float2 e = ev[((size_t)t << 15) + d];
    const float2 c = lcu[t];
    sr += e.x * c.x - e.y * c.y;
    si += e.x * c.y + e.y * c.x;
  }
  sr *= scale; si *= scale;
  mono_out[d] = make_float2(sr, si);
  const float q = qsvt[k];
  float2 a = acc[d];
  a = make_float2(fmaf(q, sr, a.x), fmaf(q, si, a.y));
  acc[d] = a;
  float m2 = fmaf(sr, sr, si * si);
  float a2 = fmaf(a.x, a.x, a.y * a.y);
  m2 = wsum(m2); a2 = wsum(a2);
  const int lane = tid & 63, wv = tid >> 6;
  if (lane == 0){ red[wv] = m2; red[8 + wv] = a2; }
  __syncthreads();
  if (tid == 0){
    float t1 = 0.f, t2 = 0.f;
    for (int i = 0; i < 8; ++i){ t1 += red[i]; t2 += red[8 + i]; }
    pMo[bid] = t1; pAo[bid] = t2;
  }
}

// ---------------- token-local barrier: padded counter, load-polling ----------
// Arrival: one RELEASE RMW per block. Poll: ACQUIRE atomic *loads* (no RMW
// serialization). Counters padded to 64B so tokens never share a cacheline.
__device__ __forceinline__ void bar_tok(unsigned* c, unsigned target){
  __syncthreads();
  if (threadIdx.x == 0){
    __hip_atomic_fetch_add(c, 1u, __ATOMIC_RELEASE, __HIP_MEMORY_SCOPE_AGENT);
    while (__hip_atomic_load(c, __ATOMIC_ACQUIRE, __HIP_MEMORY_SCOPE_AGENT) < target)
      __builtin_amdgcn_s_sleep(4);
  }
  __syncthreads();
}

// ---------------- fused per-round evolve: seg1..seg5, token barriers only ---
__global__ __launch_bounds__(512) void evolve_round_k(
    const float2* __restrict__ mono, float2* __restrict__ bufA, float2* __restrict__ bufB,
    const float2* __restrict__ csarr, const float* __restrict__ prevPM, int np,
    const float* __restrict__ qsvt, unsigned* __restrict__ tcnt, unsigned genOff)
{
  __shared__ float2 ex[4096];
  __shared__ float2 gcs[16];
  const int tid = threadIdx.x, bid = blockIdx.x;
  const int blk = bid & 7, tok = bid >> 3;
  float2* const bA = bufA + ((size_t)tok << 15);
  float2* const bB = bufB + ((size_t)tok << 15);
  const float2* const csTok = csarr + tok * NPQC;
  unsigned* const c = tcnt + tok * 16;          // 64B stride per token
  unsigned g = genOff;
  d_seg1(mono, bA, csTok, prevPM, np, 0, qsvt, tid, blk, ex, gcs);
  bar_tok(c, 8u * (++g));
  d_seg2(bA, bB, csTok, tid, blk, ex, gcs);
  bar_tok(c, 8u * (++g));
  d_seg3(bB, bA, csTok, tid, blk, ex, gcs);
  bar_tok(c, 8u * (++g));
  d_seg4(bA, bB, csTok, tid, blk, ex, gcs);
  bar_tok(c, 8u * (++g));
  d_seg5(bB, bA, csTok, tid, blk, ex, gcs);
  // grid-wide ordering to combine comes from the kernel launch boundary
}

__global__ __launch_bounds__(512) void combine2_k(const float2* __restrict__ ev, const float2* __restrict__ lcu,
    const float* __restrict__ partsPrev, int np, const float* __restrict__ qsvt, int k,
    float2* __restrict__ mono_out, float2* __restrict__ acc,
    float* __restrict__ pM, float* __restrict__ pA)
{
  __shared__ float red[16];
  d_combine(ev, lcu, partsPrev, np, qsvt, k, mono_out, acc, pM, pA, blockIdx.x, threadIdx.x, red);
}

// ---------------- final evolution + fused measurement (8 blocks) ------------
__global__ __launch_bounds__(512) void final_evolve_k(
    const float2* __restrict__ acc, float2* __restrict__ bufA, float2* __restrict__ bufB,
    float2* __restrict__ fin, const float2* __restrict__ csf,
    const float* __restrict__ pA, const float* __restrict__ qsvt,
    float* __restrict__ partials, float* __restrict__ out,
    unsigned* __restrict__ cbar, unsigned* __restrict__ done)
{
  __shared__ float2 ex[4096];
  __shared__ float2 gcs[16];
  __shared__ float sredx[8][16], sredy[8][16], sredz[8][16];
  __shared__ int lastBlk;
  const int tid = threadIdx.x, blk = blockIdx.x;
  d_seg1(acc, bufA, csf, pA, 64, 1, qsvt, tid, blk, ex, gcs);
  bar_tok(cbar, 8u);
  d_seg2(bufA, bufB, csf, tid, blk, ex, gcs);
  bar_tok(cbar, 16u);
  d_seg3(bufB, bufA, csf, tid, blk, ex, gcs);
  bar_tok(cbar, 24u);
  d_seg4(bufA, bufB, csf, tid, blk, ex, gcs);
  bar_tok(cbar, 32u);
  d_seg5(bufB, fin, csf, tid, blk, ex, gcs);
  bar_tok(cbar, 40u);

  // measurement on L1-layout fin: block covers g bits 0..11 (tid=0..8, reg=9..11)
  float2 am[8];
  #pragma unroll
  for (int r = 0; r < 8; ++r) am[r] = fin[(blk << 12) | (r << 9) | tid];
  __syncthreads();
  #pragma unroll
  for (int r = 0; r < 8; ++r) ex[(r << 9) | tid] = am[r];
  __syncthreads();
  const int lane = tid & 63, wv = tid >> 6;
  const int abit[15] = {11,10,9,8,7,6,5,4,3,2,1,0,14,13,12};   // addr bit of qubit w
  #pragma unroll
  for (int w = 0; w < 15; ++w){
    const int ab = abit[w];
    const int m = 1 << ab;
    float x = 0.f, y = 0.f, z = 0.f;
    #pragma unroll
    for (int r = 0; r < 8; ++r){
      const int g = (blk << 12) | (r << 9) | tid;
      const float2 a = am[r];
      float2 p;
      if (ab < 6){ p.x = __shfl_xor(a.x, m, 64); p.y = __shfl_xor(a.y, m, 64); }
      else if (ab < 9){ p = ex[(r << 9) | (tid ^ m)]; }
      else if (ab < 12){ p = am[r ^ (1 << (ab - 9))]; }
      else { p = fin[g ^ m]; }
      const bool lower = (g & m) == 0;
      if (lower){ x += a.x * p.x + a.y * p.y; y += a.x * p.y - a.y * p.x; }
      z += (lower ? 1.f : -1.f) * (a.x * a.x + a.y * a.y);
    }
    x = wsum(x); y = wsum(y); z = wsum(z);
    if (lane == 0){ sredx[wv][w] = x; sredy[wv][w] = y; sredz[wv][w] = z; }
  }
  __syncthreads();
  if (tid < 45){
    const int plane = tid / 15, w = tid % 15;
    float s = 0.f;
    #pragma unroll
    for (int i = 0; i < 8; ++i)
      s += (plane == 0) ? sredx[i][w] : (plane == 1) ? sredy[i][w] : sredz[i][w];
    partials[blk * 45 + tid] = (plane < 2 ? 2.f : 1.f) * s;
  }
  __syncthreads();
  if (tid == 0){
    const unsigned prev = __hip_atomic_fetch_add(done, 1u, __ATOMIC_ACQ_REL, __HIP_MEMORY_SCOPE_AGENT);
    lastBlk = (prev == 7u) ? 1 : 0;
  }
  __syncthreads();
  if (lastBlk && tid < 45){
    float s = 0.f;
    for (int i = 0; i < 8; ++i) s += partials[i * 45 + tid];
    out[tid] = s;
  }
}

// ---------------- fused setup: angles + lcu/csf prep + init + counters ------
__global__ void setup_k(const float* __restrict__ emb, const float* __restrict__ W,
                        const float* __restrict__ b, const float* __restrict__ ri,
                        const float* __restrict__ ffp, const float* __restrict__ qsvt,
                        float2* __restrict__ csarr, float2* __restrict__ lcu,
                        float2* __restrict__ csf, float2* __restrict__ monoA,
                        float2* __restrict__ acc, unsigned* __restrict__ cnts)
{
  const int bid = blockIdx.x, lane = threadIdx.x;   // 64 threads
  if (bid < 1920){
    const int p = bid % 60, t = bid / 60;
    const float* er = emb + (size_t)t * 1024;
    const float* wr = W + (size_t)p * 1024;
    float s = 0.f;
    for (int i = lane; i < 1024; i += 64) s = fmaf(er[i], wr[i], s);
    s = wsum(s);
    if (lane == 0){
      const float a = (s + b[p]) * 0.5f;
      csarr[t * NPQC + p] = make_float2(cosf(a), sinf(a));
    }
  } else {
    const int cb = bid - 1920;                      // 0..63
    const int base = cb << 9;
    #pragma unroll
    for (int j = 0; j < 8; ++j){
      const int d = base + (j << 6) + lane;
      monoA[d] = make_float2(d == 0 ? 1.f : 0.f, 0.f);
      acc[d]   = make_float2(d == 0 ? qsvt[0] : 0.f, 0.f);
    }
    if (cb == 0){
      for (int j = lane; j < 40 * 16; j += 64) cnts[j] = 0u;
    }
    if (cb == 1){
      float re = 0.f, im = 0.f, mag = 0.f;
      if (lane < NTOK){ re = ri[2 * lane]; im = ri[2 * lane + 1]; mag = sqrtf(re * re + im * im); }
      const float ssum = wsum(mag);
      const float denom = fmaxf(ssum, 1e-8f);
      if (lane < NTOK) lcu[lane] = make_float2(re / denom, im / denom);
      if (lane < NPQC){ const float a = ffp[lane] * 0.5f; csf[lane] = make_float2(cosf(a), sinf(a)); }
    }
  }
}

// ---------------- fallback multi-launch wrappers (proven round-2 path) ------

__global__ __launch_bounds__(512) void seg1_k(const float2* __restrict__ in, float2* __restrict__ out,
    const float2* __restrict__ cs, int csStride, const float* __restrict__ parts, int np,
    int finalMode, const float* __restrict__ qsvt)
{
  __shared__ float2 ex[4096]; __shared__ float2 gcs[16];
  d_seg1(in, out + ((size_t)blockIdx.y << 15), cs + blockIdx.y * csStride, parts, np, finalMode, qsvt,
         threadIdx.x, blockIdx.x, ex, gcs);
}
__global__ __launch_bounds__(512) void seg2_k(const float2* __restrict__ in, float2* __restrict__ out,
    const float2* __restrict__ cs, int csStride)
{
  __shared__ float2 ex[4096]; __shared__ float2 gcs[16];
  d_seg2(in + ((size_t)blockIdx.y << 15), out + ((size_t)blockIdx.y << 15), cs + blockIdx.y * csStride,
         threadIdx.x, blockIdx.x, ex, gcs);
}
__global__ __launch_bounds__(512) void seg3_k(const float2* __restrict__ in, float2* __restrict__ out,
    const float2* __restrict__ cs, int csStride)
{
  __shared__ float2 ex[4096]; __shared__ float2 gcs[16];
  d_seg3(in + ((size_t)blockIdx.y << 15), out + ((size_t)blockIdx.y << 15), cs + blockIdx.y * csStride,
         threadIdx.x, blockIdx.x, ex, gcs);
}
__global__ __launch_bounds__(512) void seg4_k(const float2* __restrict__ in, float2* __restrict__ out,
    const float2* __restrict__ cs, int csStride)
{
  __shared__ float2 ex[4096]; __shared__ float2 gcs[16];
  d_seg4(in + ((size_t)blockIdx.y << 15), out + ((size_t)blockIdx.y << 15), cs + blockIdx.y * csStride,
         threadIdx.x, blockIdx.x, ex, gcs);
}
__global__ __launch_bounds__(512) void seg5_k(const float2* __restrict__ in, float2* __restrict__ out,
    const float2* __restrict__ cs, int csStride)
{
  __shared__ float2 ex[4096]; __shared__ float2 gcs[16];
  d_seg5(in + ((size_t)blockIdx.y << 15), out + ((size_t)blockIdx.y << 15), cs + blockIdx.y * csStride,
         threadIdx.x, blockIdx.x, ex, gcs);
}

__global__ void measure_l1(const float2* __restrict__ st, float* __restrict__ out)
{
  __shared__ float rx[16], ryy[16], rz[16];
  const int tid = threadIdx.x;          // 1024
  const int lane = tid & 63, wv = tid >> 6;
  const int abit[15] = {11,10,9,8,7,6,5,4,3,2,1,0,14,13,12};
  for (int w = 0; w < NQ; ++w){
    const int ab = abit[w];
    const int m = 1 << ab;
    float x = 0.f, y = 0.f, z = 0.f;
    for (int d = tid; d < DIM / 2; d += 1024){
      const int i0 = ((d >> ab) << (ab + 1)) | (d & (m - 1));
      const float2 a0 = st[i0];
      const float2 a1 = st[i0 | m];
      x += a0.x * a1.x + a0.y * a1.y;
      y += a0.x * a1.y - a0.y * a1.x;
      z += (a0.x * a0.x + a0.y * a0.y) - (a1.x * a1.x + a1.y * a1.y);
    }
    x = wsum(x); y = wsum(y); z = wsum(z);
    if (lane == 0){ rx[wv] = x; ryy[wv] = y; rz[wv] = z; }
    __syncthreads();
    if (tid == 0){
      float sx = 0.f, sy = 0.f, sz = 0.f;
      for (int i = 0; i < 16; ++i){ sx += rx[i]; sy += ryy[i]; sz += rz[i]; }
      out[w] = 2.0f * sx; out[NQ + w] = 2.0f * sy; out[2 * NQ + w] = sz;
    }
    __syncthreads();
  }
}

// ============================================================================

extern "C" void kernel_launch(void* const* d_in, const int* in_sizes, int n_in,
                              void* d_out, int out_size, void* d_ws, size_t ws_size,
                              hipStream_t stream)
{
  const float* emb   = (const float*)d_in[0];
  const float* W     = (const float*)d_in[1];
  const float* b     = (const float*)d_in[2];
  const float* qsvt  = (const float*)d_in[3];
  const float* lcuri = (const float*)d_in[4];
  const float* ffp   = (const float*)d_in[5];
  float* out = (float*)d_out;

  char* ws = (char*)d_ws;
  size_t off = 0;
  auto nxt = [&](size_t bytes) { size_t o = off; off = (off + bytes + 255) & ~(size_t)255; return o; };

  const size_t o_cs   = nxt((size_t)NTOK * NPQC * sizeof(float2));
  const size_t o_csf  = nxt(NPQC * sizeof(float2));
  const size_t o_lcu2 = nxt(NTOK * sizeof(float2));
  const size_t o_pm   = nxt(3 * 64 * sizeof(float));
  const size_t o_pa   = nxt(64 * sizeof(float));
  const size_t o_part = nxt(64 * 45 * sizeof(float));
  const size_t o_cnt  = nxt(40 * 16 * sizeof(unsigned));
  const size_t o_mA2  = nxt((size_t)DIM * sizeof(float2));
  const size_t o_mB2  = nxt((size_t)DIM * sizeof(float2));
  const size_t o_acc2 = nxt((size_t)DIM * sizeof(float2));
  const size_t o_fin2 = nxt((size_t)DIM * sizeof(float2));
  const size_t o_bufA = nxt((size_t)NTOK * DIM * sizeof(float2));
  const size_t o_bufB = nxt((size_t)NTOK * DIM * sizeof(float2));
  const size_t need = off;

  float2* csarr = (float2*)(ws + o_cs);
  float2* csf   = (float2*)(ws + o_csf);
  float2* lcu   = (float2*)(ws + o_lcu2);
  float*  pMbuf = (float*)(ws + o_pm);
  float*  pA    = (float*)(ws + o_pa);
  float*  parts = (float*)(ws + o_part);
  unsigned* cnts = (unsigned*)(ws + o_cnt);
  float2* monoA = (float2*)(ws + o_mA2);
  float2* monoB = (float2*)(ws + o_mB2);
  float2* acc   = (float2*)(ws + o_acc2);
  float2* fin   = (float2*)(ws + o_fin2);
  float2* bufA  = (float2*)(ws + o_bufA);
  float2* bufB  = (float2*)(ws + o_bufB);

  setup_k<<<1984, 64, 0, stream>>>(emb, W, b, lcuri, ffp, qsvt, csarr, lcu, csf, monoA, acc, cnts);

  if (ws_size >= need) {
    // 9 launches total; grid-wide sync via launch boundaries, token-local
    // barriers (padded counters, load-polling) inside the fused round kernels.
    unsigned* tcnt = cnts;
    unsigned* fbar = cnts + 33 * 16;
    unsigned* done = cnts + 34 * 16;
    float* pM0 = pMbuf, *pM1 = pMbuf + 64, *pM2 = pMbuf + 128;

    evolve_round_k<<<256, 512, 0, stream>>>(monoA, bufA, bufB, csarr, nullptr, 0, qsvt, tcnt, 0u);
    combine2_k<<<64, 512, 0, stream>>>(bufA, lcu, nullptr, 0, qsvt, 1, monoB, acc, pM0, pA);
    evolve_round_k<<<256, 512, 0, stream>>>(monoB, bufA, bufB, csarr, pM0, 64, qsvt, tcnt, 4u);
    combine2_k<<<64, 512, 0, stream>>>(bufA, lcu, pM0, 64, qsvt, 2, monoA, acc, pM1, pA);
    evolve_round_k<<<256, 512, 0, stream>>>(monoA, bufA, bufB, csarr, pM1, 64, qsvt, tcnt, 8u);
    combine2_k<<<64, 512, 0, stream>>>(bufA, lcu, pM1, 64, qsvt, 3, monoB, acc, pM2, pA);
    final_evolve_k<<<8, 512, 0, stream>>>(acc, bufA, bufB, fin, csf, pA, qsvt, parts, out, fbar, done);
    return;
  }

  // fallback: proven multi-launch path (round 2, 334 us)
  float2* mIn = monoA;
  float2* mOut = monoB;
  const float* prevPM = nullptr;
  for (int k = 1; k <= 3; ++k) {
    const int np = prevPM ? 64 : 0;
    seg1_k<<<dim3(8, NTOK), 512, 0, stream>>>(mIn, bufA, csarr, NPQC, prevPM, np, 0, qsvt);
    seg2_k<<<dim3(8, NTOK), 512, 0, stream>>>(bufA, bufB, csarr, NPQC);
    seg3_k<<<dim3(8, NTOK), 512, 0, stream>>>(bufB, bufA, csarr, NPQC);
    seg4_k<<<dim3(8, NTOK), 512, 0, stream>>>(bufA, bufB, csarr, NPQC);
    seg5_k<<<dim3(8, NTOK), 512, 0, stream>>>(bufB, bufA, csarr, NPQC);
    float* pMk = pMbuf + (size_t)(k - 1) * 64;
    combine2_k<<<64, 512, 0, stream>>>(bufA, lcu, prevPM, np, qsvt, k, mOut, acc, pMk, pA);
    prevPM = pMk;
    float2* tmp = mIn; mIn = mOut; mOut = tmp;
  }
  seg1_k<<<dim3(8, 1), 512, 0, stream>>>(acc, bufA, csf, 0, pA, 64, 1, qsvt);
  seg2_k<<<dim3(8, 1), 512, 0, stream>>>(bufA, bufB, csf, 0);
  seg3_k<<<dim3(8, 1), 512, 0, stream>>>(bufB, bufA, csf, 0);
  seg4_k<<<dim3(8, 1), 512, 0, stream>>>(bufA, bufB, csf, 0);
  seg5_k<<<dim3(8, 1), 512, 0, stream>>>(bufB, fin, csf, 0);
  measure_l1<<<1, 1024, 0, stream>>>(fin, out);
}

// Round 8
// 310.292 us; speedup vs baseline: 2.1222x; 1.1899x over previous
//
#include <hip/hip_runtime.h>

#define NQ    15
#define DIM   32768
#define NTOK  32
#define NPQC  60

__device__ __forceinline__ float wsum(float v){
  #pragma unroll
  for (int m = 1; m < 64; m <<= 1) v += __shfl_xor(v, m, 64);
  return v;
}

// ============================================================================
// Layout machinery (proven rounds 2-5): 8 blocks per state, 12 local bits.
// Local position p: p==0 reg bit0; p 1..6 lane bits; p 7..9 tid bits 6..8 (LDS);
// p==10 reg bit1; p==11 reg bit2.  Positions 12..14 = block bits.
// ============================================================================

template<int CPOS>
__device__ __forceinline__ bool cbit(int r, int tid, int blk){
  if constexpr (CPOS < 0)        return true;
  else if constexpr (CPOS == 0)  return (r & 1) != 0;
  else if constexpr (CPOS == 10) return (r & 2) != 0;
  else if constexpr (CPOS == 11) return (r & 4) != 0;
  else if constexpr (CPOS <= 9)  return ((tid >> (CPOS - 1)) & 1) != 0;
  else                           return ((blk >> (CPOS - 12)) & 1) != 0;
}

template<int TPOS, int CPOS, bool RX>
__device__ __forceinline__ void gate_rl(float2 cs, float (&vr)[8], float (&vi)[8], int tid, int blk){
  constexpr int tm = (TPOS == 0) ? 1 : (TPOS == 10 ? 2 : 4);
  const float c = cs.x, s = cs.y;
  #pragma unroll
  for (int r0 = 0; r0 < 8; ++r0){
    if (r0 & tm) continue;
    const int r1 = r0 | tm;
    const bool act = cbit<CPOS>(r0, tid, blk);
    const float ar = vr[r0], ai = vi[r0], br = vr[r1], bi = vi[r1];
    if (act){
      if constexpr (RX){
        vr[r0] = fmaf(c, ar,  s * bi); vi[r0] = fmaf(c, ai, -s * br);
        vr[r1] = fmaf(c, br,  s * ai); vi[r1] = fmaf(c, bi, -s * ar);
      } else {
        vr[r0] = fmaf(c, ar, -s * br); vi[r0] = fmaf(c, ai, -s * bi);
        vr[r1] = fmaf(c, br,  s * ar); vi[r1] = fmaf(c, bi,  s * ai);
      }
    }
  }
}

template<int TPOS, int CPOS, bool RX>
__device__ __forceinline__ void gate_ln(float2 cs, float (&vr)[8], float (&vi)[8], int tid, int blk){
  constexpr int bm = 1 << (TPOS - 1);
  const float c = cs.x, s = cs.y;
  const int side = (tid >> (TPOS - 1)) & 1;
  const float sg = side ? s : -s;
  #pragma unroll
  for (int r = 0; r < 8; ++r){
    const float pr = __shfl_xor(vr[r], bm, 64);
    const float pi = __shfl_xor(vi[r], bm, 64);
    const bool act = cbit<CPOS>(r, tid, blk);
    float nr, ni;
    if constexpr (RX){ nr = fmaf(c, vr[r],  s * pi); ni = fmaf(c, vi[r], -s * pr); }
    else             { nr = fmaf(c, vr[r], sg * pr); ni = fmaf(c, vi[r], sg * pi); }
    if (act){ vr[r] = nr; vi[r] = ni; }
  }
}

template<int TPOS, int CPOS, bool RX>
__device__ __forceinline__ void gate_wv(float2 cs, float (&vr)[8], float (&vi)[8], int tid, int blk, float2* ex){
  constexpr int tb = TPOS - 1;                // 6..8
  const int ptid = tid ^ (1 << tb);
  const float c = cs.x, s = cs.y;
  const int side = (tid >> tb) & 1;
  const float sg = side ? s : -s;
  __syncthreads();
  #pragma unroll
  for (int r = 0; r < 8; ++r) ex[(r << 9) | tid] = make_float2(vr[r], vi[r]);
  __syncthreads();
  #pragma unroll
  for (int r = 0; r < 8; ++r){
    const float2 p = ex[(r << 9) | ptid];
    const bool act = cbit<CPOS>(r, tid, blk);
    float nr, ni;
    if constexpr (RX){ nr = fmaf(c, vr[r],  s * p.y); ni = fmaf(c, vi[r], -s * p.x); }
    else             { nr = fmaf(c, vr[r], sg * p.x); ni = fmaf(c, vi[r], sg * p.y); }
    if (act){ vr[r] = nr; vi[r] = ni; }
  }
}

template<int TPOS, int CPOS, bool RX>
__device__ __forceinline__ void G(float2 cs, float (&vr)[8], float (&vi)[8], int tid, int blk, float2* ex){
  if constexpr (TPOS == 0 || TPOS == 10 || TPOS == 11) gate_rl<TPOS,CPOS,RX>(cs, vr, vi, tid, blk);
  else if constexpr (TPOS <= 6)                        gate_ln<TPOS,CPOS,RX>(cs, vr, vi, tid, blk);
  else                                                 gate_wv<TPOS,CPOS,RX>(cs, vr, vi, tid, blk, ex);
}

#define SEG_LOAD(SRC)                                                        \
  {                                                                          \
    const int t2 = tid << 1;                                                 \
    _Pragma("unroll")                                                        \
    for (int rh = 0; rh < 4; ++rh){                                          \
      const int r2 = rh >> 1, r1 = rh & 1, ra = (r1 << 1) | (r2 << 2);       \
      const float4 v = *reinterpret_cast<const float4*>(&(SRC)[(r2 << 11) + (r1 << 10) + t2]); \
      vr[ra] = v.x; vi[ra] = v.y; vr[ra + 1] = v.z; vi[ra + 1] = v.w;        \
    }                                                                        \
  }

// ---------------- device-side segment bodies (verbatim, proven) -------------

__device__ __forceinline__ void d_seg1(const float2* __restrict__ mono, float2* __restrict__ outTok,
    const float2* __restrict__ cs, const float* __restrict__ parts, int np, int finalMode,
    const float* __restrict__ qsvt, int tid, int blk, float2* ex, float2* gcs)
{
  if (tid < 12) gcs[tid] = cs[tid];
  bool small = false; float inv = 1.f;
  if (np > 0){
    const int lane = tid & 63;
    float p = lane < np ? parts[lane] : 0.f;
    const float nv = sqrtf(wsum(p));
    if (finalMode){
      const float qs = fmaxf(fabsf(qsvt[0]) + fabsf(qsvt[1]) + fabsf(qsvt[2]) + fabsf(qsvt[3]), 1e-8f);
      small = (nv / qs) < 1e-8f;
    } else small = nv < 1e-8f;
    inv = small ? 0.f : 1.f / nv;
  }
  float vr[8], vi[8];
  const float2* src = mono + (blk << 12);
  {
    const int t2 = tid << 1;
    #pragma unroll
    for (int rh = 0; rh < 4; ++rh){
      const int r2 = rh >> 1, r1 = rh & 1, ra = (r1 << 1) | (r2 << 2);
      const float4 v = *reinterpret_cast<const float4*>(&src[(r2 << 11) + (r1 << 10) + t2]);
      vr[ra] = v.x * inv; vi[ra] = v.y * inv; vr[ra + 1] = v.z * inv; vi[ra + 1] = v.w * inv;
    }
  }
  if (small){
    #pragma unroll
    for (int r = 0; r < 8; ++r){ vr[r] = (blk == 0 && tid == 0 && r == 0) ? 1.f : 0.f; vi[r] = 0.f; }
  }
  __syncthreads();
  G<11,-1,false>(gcs[0], vr, vi, tid, blk, ex);
  G<10,-1,false>(gcs[1], vr, vi, tid, blk, ex);
  G< 9,-1,false>(gcs[2], vr, vi, tid, blk, ex);
  G< 8,-1,false>(gcs[3], vr, vi, tid, blk, ex);
  G< 7,-1,false>(gcs[4], vr, vi, tid, blk, ex);
  G< 6,-1,false>(gcs[5], vr, vi, tid, blk, ex);
  G< 5,-1,false>(gcs[6], vr, vi, tid, blk, ex);
  G< 4,-1,false>(gcs[7], vr, vi, tid, blk, ex);
  G< 3,-1,false>(gcs[8], vr, vi, tid, blk, ex);
  G< 2,-1,false>(gcs[9], vr, vi, tid, blk, ex);
  G< 1,-1,false>(gcs[10], vr, vi, tid, blk, ex);
  G< 0,-1,false>(gcs[11], vr, vi, tid, blk, ex);
  float2* dst = outTok;
  const int bb = ((blk & 1) << 5) | ((blk & 2) << 5) | ((blk & 4) << 8);
  const int tb = ((tid & 15) << 1) | ((tid & 112) << 3) | ((tid & 384) << 5);
  #pragma unroll
  for (int r1 = 0; r1 < 2; ++r1)
    #pragma unroll
    for (int r0 = 0; r0 < 2; ++r0){
      const int r = r0 | (r1 << 1);
      const int a = bb + tb + (r0 << 11) + (r1 << 14);
      *reinterpret_cast<float4*>(&dst[a]) = make_float4(vr[r], vi[r], vr[r + 4], vi[r + 4]);
    }
}

__device__ __forceinline__ void d_seg2(const float2* __restrict__ inTok, float2* __restrict__ outTok,
    const float2* __restrict__ cs, int tid, int blk, float2* ex, float2* gcs)
{
  if (tid < 15) gcs[tid] = cs[12 + tid];
  float vr[8], vi[8];
  const float2* src = inTok + (blk << 12);
  SEG_LOAD(src);
  __syncthreads();
  G<10,-1,false>(gcs[0], vr, vi, tid, blk, ex);
  G< 6,-1,false>(gcs[1], vr, vi, tid, blk, ex);
  G< 5,-1,false>(gcs[2], vr, vi, tid, blk, ex);
  G< 0, 5,true >(gcs[3], vr, vi, tid, blk, ex);
  G< 5, 6,true >(gcs[4], vr, vi, tid, blk, ex);
  G< 6,10,true >(gcs[5], vr, vi, tid, blk, ex);
  G<10,11,true >(gcs[6], vr, vi, tid, blk, ex);
  G<11, 1,true >(gcs[7], vr, vi, tid, blk, ex);
  G< 1, 2,true >(gcs[8], vr, vi, tid, blk, ex);
  G< 2, 3,true >(gcs[9], vr, vi, tid, blk, ex);
  G< 3, 4,true >(gcs[10], vr, vi, tid, blk, ex);
  G< 4, 7,true >(gcs[11], vr, vi, tid, blk, ex);
  G< 7, 8,true >(gcs[12], vr, vi, tid, blk, ex);
  G< 8, 9,true >(gcs[13], vr, vi, tid, blk, ex);
  G< 9,12,true >(gcs[14], vr, vi, tid, blk, ex);
  float2* dst = outTok;
  const int bb = ((blk & 1) << 11) | ((blk & 2) << 5) | ((blk & 4) << 3);
  const int tb = ((tid & 7) << 1) | ((tid & 8) << 7) | ((tid & 16) << 8) | ((tid & 32) << 8) | ((tid & 448) << 1);
  #pragma unroll
  for (int r1 = 0; r1 < 2; ++r1)
    #pragma unroll
    for (int r0 = 0; r0 < 2; ++r0){
      const int r = r0 | (r1 << 1);
      const int a = bb + tb + (r0 << 4) + (r1 << 14);
      *reinterpret_cast<float4*>(&dst[a]) = make_float4(vr[r], vi[r], vr[r + 4], vi[r + 4]);
    }
}

__device__ __forceinline__ void d_seg3(const float2* __restrict__ inTok, float2* __restrict__ outTok,
    const float2* __restrict__ cs, int tid, int blk, float2* ex, float2* gcs)
{
  if (tid < 15) gcs[tid] = cs[27 + tid];
  float vr[8], vi[8];
  const float2* src = inTok + (blk << 12);
  SEG_LOAD(src);
  __syncthreads();
  G<11, 6,true >(gcs[0], vr, vi, tid, blk, ex);
  G< 6, 5,true >(gcs[1], vr, vi, tid, blk, ex);
  G< 5, 4,true >(gcs[2], vr, vi, tid, blk, ex);
  G< 4,-1,false>(gcs[3], vr, vi, tid, blk, ex);
  G< 5,-1,false>(gcs[4], vr, vi, tid, blk, ex);
  G< 6,-1,false>(gcs[5], vr, vi, tid, blk, ex);
  G<11,-1,false>(gcs[6], vr, vi, tid, blk, ex);
  G< 9,-1,false>(gcs[7], vr, vi, tid, blk, ex);
  G< 8,-1,false>(gcs[8], vr, vi, tid, blk, ex);
  G< 7,-1,false>(gcs[9], vr, vi, tid, blk, ex);
  G<10,-1,false>(gcs[10], vr, vi, tid, blk, ex);
  G< 3,-1,false>(gcs[11], vr, vi, tid, blk, ex);
  G< 2,-1,false>(gcs[12], vr, vi, tid, blk, ex);
  G< 1,-1,false>(gcs[13], vr, vi, tid, blk, ex);
  G< 0,-1,false>(gcs[14], vr, vi, tid, blk, ex);
  float2* dst = outTok;
  const int bb = ((blk & 1) << 5) | ((blk & 2) << 5) | ((blk & 4) << 8);
  const int tb = ((tid & 1) << 13) | ((tid & 2) << 13) | ((tid & 60) >> 1) | ((tid & 448) << 1);
  #pragma unroll
  for (int r2 = 0; r2 < 2; ++r2)
    #pragma unroll
    for (int r0 = 0; r0 < 2; ++r0){
      const int r = r0 | (r2 << 2);
      const int a = bb + tb + (r0 << 12) + (r2 << 11);
      *reinterpret_cast<float4*>(&dst[a]) = make_float4(vr[r], vi[r], vr[r + 2], vi[r + 2]);
    }
}

__device__ __forceinline__ void d_seg4(const float2* __restrict__ inTok, float2* __restrict__ outTok,
    const float2* __restrict__ cs, int tid, int blk, float2* ex, float2* gcs)
{
  if (tid < 14) gcs[tid] = cs[42 + tid];
  float vr[8], vi[8];
  const float2* src = inTok + (blk << 12);
  SEG_LOAD(src);
  __syncthreads();
  G<10,-1,false>(gcs[0], vr, vi, tid, blk, ex);
  G< 6,-1,false>(gcs[1], vr, vi, tid, blk, ex);
  G< 5,-1,false>(gcs[2], vr, vi, tid, blk, ex);
  G< 6, 5,true >(gcs[3], vr, vi, tid, blk, ex);
  G< 5, 2,true >(gcs[4], vr, vi, tid, blk, ex);
  G< 2, 3,true >(gcs[5], vr, vi, tid, blk, ex);
  G< 3, 4,true >(gcs[6], vr, vi, tid, blk, ex);
  G< 4,11,true >(gcs[7], vr, vi, tid, blk, ex);
  G<11, 9,true >(gcs[8], vr, vi, tid, blk, ex);
  G< 9, 8,true >(gcs[9], vr, vi, tid, blk, ex);
  G< 8, 7,true >(gcs[10], vr, vi, tid, blk, ex);
  G< 7, 0,true >(gcs[11], vr, vi, tid, blk, ex);
  G< 0, 1,true >(gcs[12], vr, vi, tid, blk, ex);
  G< 1,14,true >(gcs[13], vr, vi, tid, blk, ex);
  float2* dst = outTok;
  const int bb = ((blk & 1) << 10) | ((blk & 2) << 2) | ((blk & 4) << 2);
  const int tb = ((tid & 1) << 5) | ((tid & 2) << 13) | ((tid & 4) << 11) | ((tid & 8) << 9)
               | ((tid & 48) >> 3) | ((tid & 448) << 1);
  #pragma unroll
  for (int r2 = 0; r2 < 2; ++r2)
    #pragma unroll
    for (int r0 = 0; r0 < 2; ++r0){
      const int r = r0 | (r2 << 2);
      const int a = bb + tb + (r0 << 6) + (r2 << 11);
      *reinterpret_cast<float4*>(&dst[a]) = make_float4(vr[r], vi[r], vr[r + 2], vi[r + 2]);
    }
}

__device__ __forceinline__ void d_seg5(const float2* __restrict__ inTok, float2* __restrict__ outTok,
    const float2* __restrict__ cs, int tid, int blk, float2* ex, float2* gcs)
{
  if (tid < 4) gcs[tid] = cs[56 + tid];
  float vr[8], vi[8];
  const float2* src = inTok + (blk << 12);
  SEG_LOAD(src);
  __syncthreads();
  G< 4, 3,true >(gcs[0], vr, vi, tid, blk, ex);
  G< 3,10,true >(gcs[1], vr, vi, tid, blk, ex);
  G<10, 0,true >(gcs[2], vr, vi, tid, blk, ex);
  G< 0, 2,true >(gcs[3], vr, vi, tid, blk, ex);
  float2* dst = outTok;
  const int bb = blk << 9;
  const int tb = ((tid & 1) << 12) | ((tid & 2) << 12) | ((tid & 508) >> 1);
  #pragma unroll
  for (int r2 = 0; r2 < 2; ++r2)
    #pragma unroll
    for (int r0 = 0; r0 < 2; ++r0){
      const int r = r0 | (r2 << 2);
      const int a = bb + tb + (r0 << 14) + (r2 << 8);
      *reinterpret_cast<float4*>(&dst[a]) = make_float4(vr[r], vi[r], vr[r + 2], vi[r + 2]);
    }
}

__device__ __forceinline__ void d_combine(const float2* __restrict__ ev, const float2* __restrict__ lcu,
    const float* __restrict__ partsPrev, int np, const float* __restrict__ qsvt, int k,
    float2* __restrict__ mono_out, float2* __restrict__ acc,
    float* __restrict__ pMo, float* __restrict__ pAo, int bid, int tid, float* red)
{
  const int d = (bid << 9) | tid;
  float scale = 1.f;
  if (np > 0){
    const int lane = tid & 63;
    float p = lane < np ? partsPrev[lane] : 0.f;
    const float nv = sqrtf(wsum(p));
    scale = (nv < 1e-8f) ? 1.f : nv;
  }
  float sr = 0.f, si = 0.f;
  #pragma unroll
  for (int t = 0; t < NTOK; ++t){
    const float2 e = ev[((size_t)t << 15) + d];
    const float2 c = lcu[t];
    sr += e.x * c.x - e.y * c.y;
    si += e.x * c.y + e.y * c.x;
  }
  sr *= scale; si *= scale;
  mono_out[d] = make_float2(sr, si);
  const float q = qsvt[k];
  float2 a = acc[d];
  a = make_float2(fmaf(q, sr, a.x), fmaf(q, si, a.y));
  acc[d] = a;
  float m2 = fmaf(sr, sr, si * si);
  float a2 = fmaf(a.x, a.x, a.y * a.y);
  m2 = wsum(m2); a2 = wsum(a2);
  const int lane = tid & 63, wv = tid >> 6;
  if (lane == 0){ red[wv] = m2; red[8 + wv] = a2; }
  __syncthreads();
  if (tid == 0){
    float t1 = 0.f, t2 = 0.f;
    for (int i = 0; i < 8; ++i){ t1 += red[i]; t2 += red[8 + i]; }
    pMo[bid] = t1; pAo[bid] = t2;
  }
}

// ---------------- token-local barrier ----------------------------------------
// Arrival: one RELEASE RMW. Poll: RELAXED loads (NO per-iteration cache
// invalidation — round-5's ACQUIRE-in-loop was the 16us/barrier bug), then a
// single agent-scope ACQUIRE fence once the target is reached (via the LLVM
// builtin: __hip_atomic_fence does not exist in this ROCm's headers).
__device__ __forceinline__ void bar_tok(unsigned* c, unsigned target){
  __syncthreads();
  if (threadIdx.x == 0){
    __hip_atomic_fetch_add(c, 1u, __ATOMIC_RELEASE, __HIP_MEMORY_SCOPE_AGENT);
    while (__hip_atomic_load(c, __ATOMIC_RELAXED, __HIP_MEMORY_SCOPE_AGENT) < target)
      __builtin_amdgcn_s_sleep(1);
    __builtin_amdgcn_fence(__ATOMIC_ACQUIRE, "agent");
  }
  __syncthreads();
}

// ---------------- fused per-round evolve: seg1..seg5, token barriers only ---
// Block mapping tok = bid & 31, blk = bid >> 5: a token's 8 blocks share
// bid%8, i.e. land on the SAME XCD under round-robin dispatch -> the 512 KB
// per-token exchange stays in that XCD's 4 MB L2 (perf-only assumption;
// correctness still via agent-scope fences).
__global__ __launch_bounds__(512) void evolve_round_k(
    const float2* __restrict__ mono, float2* __restrict__ bufA, float2* __restrict__ bufB,
    const float2* __restrict__ csarr, const float* __restrict__ prevPM, int np,
    const float* __restrict__ qsvt, unsigned* __restrict__ tcnt, unsigned genOff)
{
  __shared__ float2 ex[4096];
  __shared__ float2 gcs[16];
  const int tid = threadIdx.x, bid = blockIdx.x;
  const int tok = bid & 31, blk = bid >> 5;
  float2* const bA = bufA + ((size_t)tok << 15);
  float2* const bB = bufB + ((size_t)tok << 15);
  const float2* const csTok = csarr + tok * NPQC;
  unsigned* const c = tcnt + tok * 16;          // 64B stride per token
  unsigned g = genOff;
  d_seg1(mono, bA, csTok, prevPM, np, 0, qsvt, tid, blk, ex, gcs);
  bar_tok(c, 8u * (++g));
  d_seg2(bA, bB, csTok, tid, blk, ex, gcs);
  bar_tok(c, 8u * (++g));
  d_seg3(bB, bA, csTok, tid, blk, ex, gcs);
  bar_tok(c, 8u * (++g));
  d_seg4(bA, bB, csTok, tid, blk, ex, gcs);
  bar_tok(c, 8u * (++g));
  d_seg5(bB, bA, csTok, tid, blk, ex, gcs);
  // grid-wide ordering to combine comes from the kernel launch boundary
}

__global__ __launch_bounds__(512) void combine2_k(const float2* __restrict__ ev, const float2* __restrict__ lcu,
    const float* __restrict__ partsPrev, int np, const float* __restrict__ qsvt, int k,
    float2* __restrict__ mono_out, float2* __restrict__ acc,
    float* __restrict__ pM, float* __restrict__ pA)
{
  __shared__ float red[16];
  d_combine(ev, lcu, partsPrev, np, qsvt, k, mono_out, acc, pM, pA, blockIdx.x, threadIdx.x, red);
}

// ---------------- final evolution + fused measurement (8 blocks) ------------
__global__ __launch_bounds__(512) void final_evolve_k(
    const float2* __restrict__ acc, float2* __restrict__ bufA, float2* __restrict__ bufB,
    float2* __restrict__ fin, const float2* __restrict__ csf,
    const float* __restrict__ pA, const float* __restrict__ qsvt,
    float* __restrict__ partials, float* __restrict__ out,
    unsigned* __restrict__ cbar, unsigned* __restrict__ done)
{
  __shared__ float2 ex[4096];
  __shared__ float2 gcs[16];
  __shared__ float sredx[8][16], sredy[8][16], sredz[8][16];
  __shared__ int lastBlk;
  const int tid = threadIdx.x, blk = blockIdx.x;
  d_seg1(acc, bufA, csf, pA, 64, 1, qsvt, tid, blk, ex, gcs);
  bar_tok(cbar, 8u);
  d_seg2(bufA, bufB, csf, tid, blk, ex, gcs);
  bar_tok(cbar, 16u);
  d_seg3(bufB, bufA, csf, tid, blk, ex, gcs);
  bar_tok(cbar, 24u);
  d_seg4(bufA, bufB, csf, tid, blk, ex, gcs);
  bar_tok(cbar, 32u);
  d_seg5(bufB, fin, csf, tid, blk, ex, gcs);
  bar_tok(cbar, 40u);

  // measurement on L1-layout fin: block covers g bits 0..11 (tid=0..8, reg=9..11)
  float2 am[8];
  #pragma unroll
  for (int r = 0; r < 8; ++r) am[r] = fin[(blk << 12) | (r << 9) | tid];
  __syncthreads();
  #pragma unroll
  for (int r = 0; r < 8; ++r) ex[(r << 9) | tid] = am[r];
  __syncthreads();
  const int lane = tid & 63, wv = tid >> 6;
  const int abit[15] = {11,10,9,8,7,6,5,4,3,2,1,0,14,13,12};   // addr bit of qubit w
  #pragma unroll
  for (int w = 0; w < 15; ++w){
    const int ab = abit[w];
    const int m = 1 << ab;
    float x = 0.f, y = 0.f, z = 0.f;
    #pragma unroll
    for (int r = 0; r < 8; ++r){
      const int g = (blk << 12) | (r << 9) | tid;
      const float2 a = am[r];
      float2 p;
      if (ab < 6){ p.x = __shfl_xor(a.x, m, 64); p.y = __shfl_xor(a.y, m, 64); }
      else if (ab < 9){ p = ex[(r << 9) | (tid ^ m)]; }
      else if (ab < 12){ p = am[r ^ (1 << (ab - 9))]; }
      else { p = fin[g ^ m]; }
      const bool lower = (g & m) == 0;
      if (lower){ x += a.x * p.x + a.y * p.y; y += a.x * p.y - a.y * p.x; }
      z += (lower ? 1.f : -1.f) * (a.x * a.x + a.y * a.y);
    }
    x = wsum(x); y = wsum(y); z = wsum(z);
    if (lane == 0){ sredx[wv][w] = x; sredy[wv][w] = y; sredz[wv][w] = z; }
  }
  __syncthreads();
  if (tid < 45){
    const int plane = tid / 15, w = tid % 15;
    float s = 0.f;
    #pragma unroll
    for (int i = 0; i < 8; ++i)
      s += (plane == 0) ? sredx[i][w] : (plane == 1) ? sredy[i][w] : sredz[i][w];
    partials[blk * 45 + tid] = (plane < 2 ? 2.f : 1.f) * s;
  }
  __syncthreads();
  if (tid == 0){
    const unsigned prev = __hip_atomic_fetch_add(done, 1u, __ATOMIC_ACQ_REL, __HIP_MEMORY_SCOPE_AGENT);
    lastBlk = (prev == 7u) ? 1 : 0;
  }
  __syncthreads();
  if (lastBlk && tid < 45){
    float s = 0.f;
    for (int i = 0; i < 8; ++i) s += partials[i * 45 + tid];
    out[tid] = s;
  }
}

// ---------------- fused setup: angles + lcu/csf prep + init + counters ------
__global__ void setup_k(const float* __restrict__ emb, const float* __restrict__ W,
                        const float* __restrict__ b, const float* __restrict__ ri,
                        const float* __restrict__ ffp, const float* __restrict__ qsvt,
                        float2* __restrict__ csarr, float2* __restrict__ lcu,
                        float2* __restrict__ csf, float2* __restrict__ monoA,
                        float2* __restrict__ acc, unsigned* __restrict__ cnts)
{
  const int bid = blockIdx.x, lane = threadIdx.x;   // 64 threads
  if (bid < 1920){
    const int p = bid % 60, t = bid / 60;
    const float4* er = reinterpret_cast<const float4*>(emb + (size_t)t * 1024);
    const float4* wr = reinterpret_cast<const float4*>(W + (size_t)p * 1024);
    float s = 0.f;
    #pragma unroll
    for (int i = 0; i < 4; ++i){
      const float4 e = er[lane + (i << 6)];
      const float4 w = wr[lane + (i << 6)];
      s = fmaf(e.x, w.x, s); s = fmaf(e.y, w.y, s);
      s = fmaf(e.z, w.z, s); s = fmaf(e.w, w.w, s);
    }
    s = wsum(s);
    if (lane == 0){
      const float a = (s + b[p]) * 0.5f;
      csarr[t * NPQC + p] = make_float2(cosf(a), sinf(a));
    }
  } else {
    const int cb = bid - 1920;                      // 0..63
    const int base = cb << 9;
    #pragma unroll
    for (int j = 0; j < 8; ++j){
      const int d = base + (j << 6) + lane;
      monoA[d] = make_float2(d == 0 ? 1.f : 0.f, 0.f);
      acc[d]   = make_float2(d == 0 ? qsvt[0] : 0.f, 0.f);
    }
    if (cb == 0){
      for (int j = lane; j < 40 * 16; j += 64) cnts[j] = 0u;
    }
    if (cb == 1){
      float re = 0.f, im = 0.f, mag = 0.f;
      if (lane < NTOK){ re = ri[2 * lane]; im = ri[2 * lane + 1]; mag = sqrtf(re * re + im * im); }
      const float ssum = wsum(mag);
      const float denom = fmaxf(ssum, 1e-8f);
      if (lane < NTOK) lcu[lane] = make_float2(re / denom, im / denom);
      if (lane < NPQC){ const float a = ffp[lane] * 0.5f; csf[lane] = make_float2(cosf(a), sinf(a)); }
    }
  }
}

// ---------------- fallback multi-launch wrappers (proven round-2 path) ------

__global__ __launch_bounds__(512) void seg1_k(const float2* __restrict__ in, float2* __restrict__ out,
    const float2* __restrict__ cs, int csStride, const float* __restrict__ parts, int np,
    int finalMode, const float* __restrict__ qsvt)
{
  __shared__ float2 ex[4096]; __shared__ float2 gcs[16];
  d_seg1(in, out + ((size_t)blockIdx.y << 15), cs + blockIdx.y * csStride, parts, np, finalMode, qsvt,
         threadIdx.x, blockIdx.x, ex, gcs);
}
__global__ __launch_bounds__(512) void seg2_k(const float2* __restrict__ in, float2* __restrict__ out,
    const float2* __restrict__ cs, int csStride)
{
  __shared__ float2 ex[4096]; __shared__ float2 gcs[16];
  d_seg2(in + ((size_t)blockIdx.y << 15), out + ((size_t)blockIdx.y << 15), cs + blockIdx.y * csStride,
         threadIdx.x, blockIdx.x, ex, gcs);
}
__global__ __launch_bounds__(512) void seg3_k(const float2* __restrict__ in, float2* __restrict__ out,
    const float2* __restrict__ cs, int csStride)
{
  __shared__ float2 ex[4096]; __shared__ float2 gcs[16];
  d_seg3(in + ((size_t)blockIdx.y << 15), out + ((size_t)blockIdx.y << 15), cs + blockIdx.y * csStride,
         threadIdx.x, blockIdx.x, ex, gcs);
}
__global__ __launch_bounds__(512) void seg4_k(const float2* __restrict__ in, float2* __restrict__ out,
    const float2* __restrict__ cs, int csStride)
{
  __shared__ float2 ex[4096]; __shared__ float2 gcs[16];
  d_seg4(in + ((size_t)blockIdx.y << 15), out + ((size_t)blockIdx.y << 15), cs + blockIdx.y * csStride,
         threadIdx.x, blockIdx.x, ex, gcs);
}
__global__ __launch_bounds__(512) void seg5_k(const float2* __restrict__ in, float2* __restrict__ out,
    const float2* __restrict__ cs, int csStride)
{
  __shared__ float2 ex[4096]; __shared__ float2 gcs[16];
  d_seg5(in + ((size_t)blockIdx.y << 15), out + ((size_t)blockIdx.y << 15), cs + blockIdx.y * csStride,
         threadIdx.x, blockIdx.x, ex, gcs);
}

__global__ void measure_l1(const float2* __restrict__ st, float* __restrict__ out)
{
  __shared__ float rx[16], ryy[16], rz[16];
  const int tid = threadIdx.x;          // 1024
  const int lane = tid & 63, wv = tid >> 6;
  const int abit[15] = {11,10,9,8,7,6,5,4,3,2,1,0,14,13,12};
  for (int w = 0; w < NQ; ++w){
    const int ab = abit[w];
    const int m = 1 << ab;
    float x = 0.f, y = 0.f, z = 0.f;
    for (int d = tid; d < DIM / 2; d += 1024){
      const int i0 = ((d >> ab) << (ab + 1)) | (d & (m - 1));
      const float2 a0 = st[i0];
      const float2 a1 = st[i0 | m];
      x += a0.x * a1.x + a0.y * a1.y;
      y += a0.x * a1.y - a0.y * a1.x;
      z += (a0.x * a0.x + a0.y * a0.y) - (a1.x * a1.x + a1.y * a1.y);
    }
    x = wsum(x); y = wsum(y); z = wsum(z);
    if (lane == 0){ rx[wv] = x; ryy[wv] = y; rz[wv] = z; }
    __syncthreads();
    if (tid == 0){
      float sx = 0.f, sy = 0.f, sz = 0.f;
      for (int i = 0; i < 16; ++i){ sx += rx[i]; sy += ryy[i]; sz += rz[i]; }
      out[w] = 2.0f * sx; out[NQ + w] = 2.0f * sy; out[2 * NQ + w] = sz;
    }
    __syncthreads();
  }
}

// ============================================================================

extern "C" void kernel_launch(void* const* d_in, const int* in_sizes, int n_in,
                              void* d_out, int out_size, void* d_ws, size_t ws_size,
                              hipStream_t stream)
{
  const float* emb   = (const float*)d_in[0];
  const float* W     = (const float*)d_in[1];
  const float* b     = (const float*)d_in[2];
  const float* qsvt  = (const float*)d_in[3];
  const float* lcuri = (const float*)d_in[4];
  const float* ffp   = (const float*)d_in[5];
  float* out = (float*)d_out;

  char* ws = (char*)d_ws;
  size_t off = 0;
  auto nxt = [&](size_t bytes) { size_t o = off; off = (off + bytes + 255) & ~(size_t)255; return o; };

  const size_t o_cs   = nxt((size_t)NTOK * NPQC * sizeof(float2));
  const size_t o_csf  = nxt(NPQC * sizeof(float2));
  const size_t o_lcu2 = nxt(NTOK * sizeof(float2));
  const size_t o_pm   = nxt(3 * 64 * sizeof(float));
  const size_t o_pa   = nxt(64 * sizeof(float));
  const size_t o_part = nxt(64 * 45 * sizeof(float));
  const size_t o_cnt  = nxt(40 * 16 * sizeof(unsigned));
  const size_t o_mA2  = nxt((size_t)DIM * sizeof(float2));
  const size_t o_mB2  = nxt((size_t)DIM * sizeof(float2));
  const size_t o_acc2 = nxt((size_t)DIM * sizeof(float2));
  const size_t o_fin2 = nxt((size_t)DIM * sizeof(float2));
  const size_t o_bufA = nxt((size_t)NTOK * DIM * sizeof(float2));
  const size_t o_bufB = nxt((size_t)NTOK * DIM * sizeof(float2));
  const size_t need = off;

  float2* csarr = (float2*)(ws + o_cs);
  float2* csf   = (float2*)(ws + o_csf);
  float2* lcu   = (float2*)(ws + o_lcu2);
  float*  pMbuf = (float*)(ws + o_pm);
  float*  pA    = (float*)(ws + o_pa);
  float*  parts = (float*)(ws + o_part);
  unsigned* cnts = (unsigned*)(ws + o_cnt);
  float2* monoA = (float2*)(ws + o_mA2);
  float2* monoB = (float2*)(ws + o_mB2);
  float2* acc   = (float2*)(ws + o_acc2);
  float2* fin   = (float2*)(ws + o_fin2);
  float2* bufA  = (float2*)(ws + o_bufA);
  float2* bufB  = (float2*)(ws + o_bufB);

  setup_k<<<1984, 64, 0, stream>>>(emb, W, b, lcuri, ffp, qsvt, csarr, lcu, csf, monoA, acc, cnts);

  if (ws_size >= need) {
    // 9 launches total; grid-wide sync via launch boundaries, token-local
    // barriers (padded counters, relaxed polling) inside the fused round kernels.
    unsigned* tcnt = cnts;
    unsigned* fbar = cnts + 33 * 16;
    unsigned* done = cnts + 34 * 16;
    float* pM0 = pMbuf, *pM1 = pMbuf + 64, *pM2 = pMbuf + 128;

    evolve_round_k<<<256, 512, 0, stream>>>(monoA, bufA, bufB, csarr, nullptr, 0, qsvt, tcnt, 0u);
    combine2_k<<<64, 512, 0, stream>>>(bufA, lcu, nullptr, 0, qsvt, 1, monoB, acc, pM0, pA);
    evolve_round_k<<<256, 512, 0, stream>>>(monoB, bufA, bufB, csarr, pM0, 64, qsvt, tcnt, 4u);
    combine2_k<<<64, 512, 0, stream>>>(bufA, lcu, pM0, 64, qsvt, 2, monoA, acc, pM1, pA);
    evolve_round_k<<<256, 512, 0, stream>>>(monoA, bufA, bufB, csarr, pM1, 64, qsvt, tcnt, 8u);
    combine2_k<<<64, 512, 0, stream>>>(bufA, lcu, pM1, 64, qsvt, 3, monoB, acc, pM2, pA);
    final_evolve_k<<<8, 512, 0, stream>>>(acc, bufA, bufB, fin, csf, pA, qsvt, parts, out, fbar, done);
    return;
  }

  // fallback: proven multi-launch path (round 2, 334 us)
  float2* mIn = monoA;
  float2* mOut = monoB;
  const float* prevPM = nullptr;
  for (int k = 1; k <= 3; ++k) {
    const int np = prevPM ? 64 : 0;
    seg1_k<<<dim3(8, NTOK), 512, 0, stream>>>(mIn, bufA, csarr, NPQC, prevPM, np, 0, qsvt);
    seg2_k<<<dim3(8, NTOK), 512, 0, stream>>>(bufA, bufB, csarr, NPQC);
    seg3_k<<<dim3(8, NTOK), 512, 0, stream>>>(bufB, bufA, csarr, NPQC);
    seg4_k<<<dim3(8, NTOK), 512, 0, stream>>>(bufA, bufB, csarr, NPQC);
    seg5_k<<<dim3(8, NTOK), 512, 0, stream>>>(bufB, bufA, csarr, NPQC);
    float* pMk = pMbuf + (size_t)(k - 1) * 64;
    combine2_k<<<64, 512, 0, stream>>>(bufA, lcu, prevPM, np, qsvt, k, mOut, acc, pMk, pA);
    prevPM = pMk;
    float2* tmp = mIn; mIn = mOut; mOut = tmp;
  }
  seg1_k<<<dim3(8, 1), 512, 0, stream>>>(acc, bufA, csf, 0, pA, 64, 1, qsvt);
  seg2_k<<<dim3(8, 1), 512, 0, stream>>>(bufA, bufB, csf, 0);
  seg3_k<<<dim3(8, 1), 512, 0, stream>>>(bufB, bufA, csf, 0);
  seg4_k<<<dim3(8, 1), 512, 0, stream>>>(bufA, bufB, csf, 0);
  seg5_k<<<dim3(8, 1), 512, 0, stream>>>(bufB, fin, csf, 0);
  measure_l1<<<1, 1024, 0, stream>>>(fin, out);
}